// Round 18
// baseline (109.714 us; speedup 1.0000x reference)
//
#include <hip/hip_runtime.h>
#include <hip/hip_bf16.h>
#include <stdint.h>

#define EMBED 1024
#define NH 16
#define HD 64
#define BATCH 2
#define SEQ 2048
#define MTOK (BATCH*SEQ)   // 4096

using bf8 = __attribute__((ext_vector_type(8))) short;     // 8 bf16 = one MFMA A/B frag
using f4  = __attribute__((ext_vector_type(4))) float;     // 16x16 C/D frag
using f16v = __attribute__((ext_vector_type(16))) float;   // 32x32 C/D frag
using u16x4 = __attribute__((ext_vector_type(4))) unsigned short;

union U4 { uint32_t u[4]; bf8 v; };

__device__ __forceinline__ uint32_t pk_bf16(float a, float b) {
  __hip_bfloat162 h = __float22bfloat162_rn(float2{a, b});
  union { __hip_bfloat162 h; uint32_t u; } c; c.h = h; return c.u;
}
__device__ __forceinline__ unsigned short bfbits(float f) {
  __hip_bfloat16 h = __float2bfloat16(f);
  union { __hip_bfloat16 h; unsigned short u; } c; c.h = h; return c.u;
}
__device__ __forceinline__ float bf2f(unsigned short u) {
  union { uint32_t u; float f; } c; c.u = (uint32_t)u << 16; return c.f;
}
__device__ __forceinline__ float fexp2(float x) {
#if __has_builtin(__builtin_amdgcn_exp2f)
  return __builtin_amdgcn_exp2f(x);
#else
  return exp2f(x);
#endif
}
__device__ __forceinline__ float frcp(float x) {
#if __has_builtin(__builtin_amdgcn_rcpf)
  return __builtin_amdgcn_rcpf(x);
#else
  return 1.f / x;
#endif
}

__device__ __forceinline__ void gl2lds16(const void* g, void* l) {
  __builtin_amdgcn_global_load_lds(
      (const __attribute__((address_space(1))) void*)g,
      (__attribute__((address_space(3))) void*)l, 16, 0, 0);
}

// ---------------- fused prep: x->bf16 | Wqkv transpose | Wout transpose ----------------
__global__ __launch_bounds__(256) void prep(const float* __restrict__ x,
                                            unsigned short* __restrict__ xb,
                                            const float* __restrict__ Wqkv,
                                            unsigned short* __restrict__ wqkvT,
                                            const float* __restrict__ Wout,
                                            unsigned short* __restrict__ woutT) {
  __shared__ float tl[64][65];
  int blk = blockIdx.x;
  if (blk < 4096) {                              // fp32 -> bf16, 1024 elems/block
    int i = (blk * 256 + threadIdx.x) * 4;
    float4 v = *(const float4*)(x + i);
    uint2 o;
    o.x = pk_bf16(v.x, v.y);
    o.y = pk_bf16(v.z, v.w);
    *(uint2*)(xb + i) = o;
    return;
  }
  const float* W; unsigned short* Wt; int K, N, bx, by;
  if (blk < 4096 + 768) {
    int j = blk - 4096; W = Wqkv; Wt = wqkvT; K = 1024; N = 3072;
    bx = j % 48; by = j / 48;
  } else {
    int j = blk - 4096 - 768; W = Wout; Wt = woutT; K = 1024; N = 1024;
    bx = j % 16; by = j / 16;
  }
  int k0 = by * 64, n0 = bx * 64;
  int tr = threadIdx.x >> 6, tc = threadIdx.x & 63;
#pragma unroll
  for (int i = 0; i < 16; i++) {
    int r = tr + i * 4;
    tl[r][tc] = W[(size_t)(k0 + r) * N + n0 + tc];
  }
  __syncthreads();
#pragma unroll
  for (int i = 0; i < 16; i++) {
    int r = tr + i * 4;
    Wt[(size_t)(n0 + r) * K + k0 + tc] = bfbits(tl[tc][r]);
  }
}

// ---------------- 8-phase-style 256x256 GEMM (gemm1): qkv = xb * wqkvT^T + bias --------
// 512 thr = 8 waves (2M x 4N), per-wave 128x64 out (8 m-frags x 4 n-frags), BK=64.
// LDS 128 KB: A dbuf 2x32K @0, B dbuf 2x32K @65536. Per K-tile: 4 phases, each
// {stage-dead-quarter(T+2) | ds_read | MFMA(16) | barrier}; vmcnt(7) once per tile
// at p0 (tile T retired; T+1's 7 in flight). B-frags read once (p0), held in regs.
// Quarter-safety: A-quarter q_{p-1}(T) reads finish at phase p-1's end barrier, so
// staging q_{p-1}(T+2) into the same buffer during phase p is race-free; B(T) is
// fully read in p0, so B(T+2) staging occupies phases 1-3. A-q3(T+1) spills to (T+1,p0).
__global__ __launch_bounds__(512, 2) void gemm8(const unsigned short* __restrict__ A,
                                                const unsigned short* __restrict__ Bt,
                                                const float* __restrict__ bias,
                                                unsigned short* __restrict__ Oq,
                                                unsigned short* __restrict__ Ov,
                                                int M, int N, int K) {
  const int tid = threadIdx.x;
  const int w = tid >> 6, lane = tid & 63;
  const int wm = w >> 2, wn = w & 3;             // 2M x 4N waves
  const int m0 = blockIdx.y * 256, n0 = blockIdx.x * 256;

  __shared__ char smem[131072];

  f4 acc[8][4] = {};

  auto stA = [&](int buf, int kk, int ca) {      // one 8-row A chunk (ca in 0..31)
    int row = ca * 8 + (lane >> 3);
    int col = ((lane & 7) * 8) ^ ((row & 7) << 3);
    gl2lds16(A + (size_t)(m0 + row) * K + kk * 64 + col, smem + buf * 32768 + ca * 1024);
  };
  auto stB = [&](int buf, int kk, int cb) {
    int row = cb * 8 + (lane >> 3);
    int col = ((lane & 7) * 8) ^ ((row & 7) << 3);
    gl2lds16(Bt + (size_t)(n0 + row) * K + kk * 64 + col, smem + 65536 + buf * 32768 + cb * 1024);
  };

  const int nk = K / 64;
  // prologue: tiles 0 and 1 fully staged (8 loads/thread each)
#pragma unroll
  for (int c = 0; c < 4; c++) stA(0, 0, c * 8 + w);
#pragma unroll
  for (int c = 0; c < 4; c++) stB(0, 0, c * 8 + w);
#pragma unroll
  for (int c = 0; c < 4; c++) stA(1, 1, c * 8 + w);
#pragma unroll
  for (int c = 0; c < 4; c++) stB(1, 1, c * 8 + w);

  for (int T = 0; T < nk; T++) {
    const int buf = T & 1;
    const char* Al = smem + buf * 32768;
    const char* Bl = smem + 65536 + buf * 32768;

    // ---- phase 0 ----
    if (T + 1 < nk) { asm volatile("s_waitcnt vmcnt(7)" ::: "memory"); }
    else            { asm volatile("s_waitcnt vmcnt(0)" ::: "memory"); }
    __builtin_amdgcn_s_barrier();                // tile T fully visible to all waves
    if (T >= 1 && T + 1 < nk) {                  // spill: A-q3(T+1) (rows 96-127 & 224-255)
      int ca = (w < 4) ? (12 + w) : (24 + w);
      stA((T + 1) & 1, T + 1, ca);
    }
    bf8 bfrag[4][2];
#pragma unroll
    for (int nt = 0; nt < 4; nt++) {             // B frags for whole tile (8 reads)
      int rr = wn * 64 + nt * 16 + (lane & 15);
#pragma unroll
      for (int ks = 0; ks < 2; ks++)
        bfrag[nt][ks] = *(const bf8*)(Bl + rr * 128 + ((ks * 64 + (lane >> 4) * 16) ^ ((rr & 7) << 4)));
    }
    {
      bf8 af[2][2];
#pragma unroll
      for (int i = 0; i < 2; i++) {
        int rr = wm * 128 + i * 16 + (lane & 15);          // m-frags 0,1
#pragma unroll
        for (int ks = 0; ks < 2; ks++)
          af[i][ks] = *(const bf8*)(Al + rr * 128 + ((ks * 64 + (lane >> 4) * 16) ^ ((rr & 7) << 4)));
      }
      __builtin_amdgcn_s_setprio(1);
#pragma unroll
      for (int i = 0; i < 2; i++)
#pragma unroll
        for (int nt = 0; nt < 4; nt++)
#pragma unroll
          for (int ks = 0; ks < 2; ks++)
            acc[i][nt] = __builtin_amdgcn_mfma_f32_16x16x32_bf16(af[i][ks], bfrag[nt][ks], acc[i][nt], 0, 0, 0);
      __builtin_amdgcn_s_setprio(0);
    }
    __builtin_amdgcn_s_barrier();                // all waves done reading A-q0(T), B(T)

    // ---- phases 1..3 ----
#pragma unroll
    for (int p = 1; p < 4; p++) {
      if (T + 2 < nk) {                          // stage into buf (T+2)&1 == buf (dead regions)
        int ca = (w < 4) ? (4 * (p - 1) + w) : (16 + 4 * (p - 1) + (w - 4));  // A-q_{p-1}
        stA(buf, T + 2, ca);
        if (p == 1)      { stB(buf, T + 2, w * 2); stB(buf, T + 2, w * 2 + 1); }
        else if (p == 2) { stB(buf, T + 2, 16 + w); }
        else             { stB(buf, T + 2, 24 + w); }
      }
      bf8 af[2][2];
#pragma unroll
      for (int i = 0; i < 2; i++) {
        int rr = wm * 128 + (2 * p + i) * 16 + (lane & 15);
#pragma unroll
        for (int ks = 0; ks < 2; ks++)
          af[i][ks] = *(const bf8*)(Al + rr * 128 + ((ks * 64 + (lane >> 4) * 16) ^ ((rr & 7) << 4)));
      }
      __builtin_amdgcn_s_setprio(1);
#pragma unroll
      for (int i = 0; i < 2; i++)
#pragma unroll
        for (int nt = 0; nt < 4; nt++)
#pragma unroll
          for (int ks = 0; ks < 2; ks++)
            acc[2 * p + i][nt] = __builtin_amdgcn_mfma_f32_16x16x32_bf16(af[i][ks], bfrag[nt][ks], acc[2 * p + i][nt], 0, 0, 0);
      __builtin_amdgcn_s_setprio(0);
      __builtin_amdgcn_s_barrier();              // quarter q_p(T) reads retired
    }
  }

  // ---- epilogue: scatter Q/K (scaled) and V-transposed ----
  const int region = n0 >> 10;                   // block n-span 256, aligned -> uniform? no:
  // n0 multiples of 256; region boundary at 1024 -> n0..n0+255 stays in one region. OK.
  if (region < 2) {
    float sc = (region == 0) ? 0.180336880f : 1.0f;
#pragma unroll
    for (int nt = 0; nt < 4; nt++) {
      int n = n0 + wn * 64 + nt * 16 + (lane & 15);
      float bv = bias[n];
      int c = n & 1023, h = c >> 6, d = c & 63;
#pragma unroll
      for (int mf = 0; mf < 8; mf++) {
#pragma unroll
        for (int r = 0; r < 4; r++) {
          int m = m0 + wm * 128 + mf * 16 + (lane >> 4) * 4 + r;
          int b = m >> 11, t = m & 2047;
          size_t off = ((((size_t)region * 2 + b) * 16 + h) * 2048 + t) * 64 + d;
          Oq[off] = bfbits((acc[mf][nt][r] + bv) * sc);
        }
      }
    }
  } else {                                       // V transposed, t-contiguous b64
#pragma unroll
    for (int nt = 0; nt < 4; nt++) {
      int n = n0 + wn * 64 + nt * 16 + (lane & 15);
      float bv = bias[n];
      int c = n & 1023, h = c >> 6, d = c & 63;
#pragma unroll
      for (int mf = 0; mf < 8; mf++) {
        int m = m0 + wm * 128 + mf * 16 + (lane >> 4) * 4;
        int b = m >> 11, t = m & 2047;
        size_t off = (((size_t)b * 16 + h) * 64 + d) * 2048 + t;
        u16x4 pk4;
#pragma unroll
        for (int r = 0; r < 4; r++) pk4[r] = bfbits(acc[mf][nt][r] + bv);
        *(u16x4*)(Ov + off) = pk4;
      }
    }
  }
}

// ---------------- pipelined bf16 GEMM (gemm2): 2-phase counted-vmcnt ----------------
template<int BN, int MODE>
__global__ __launch_bounds__(256) void gemm_bt(const unsigned short* __restrict__ A,
                                               const unsigned short* __restrict__ Bt,
                                               const float* __restrict__ bias,
                                               unsigned short* __restrict__ Oq,
                                               unsigned short* __restrict__ Ov,
                                               float* __restrict__ Of,
                                               int M, int N, int K) {
  constexpr int MT = (BN == 128) ? 4 : 2;
  constexpr int BB = BN * 128;                   // bytes per B buffer
  const int tid = threadIdx.x;
  const int w = tid >> 6, lane = tid & 63;
  const int wm = (BN == 128) ? (w >> 1) : w;
  const int wn = (BN == 128) ? (w & 1) : 0;
  const int m0 = blockIdx.y * 128, n0 = blockIdx.x * BN;

  __shared__ char smem[32768 + 2 * BB];          // A dbuf 2x16K | B dbuf 2xBB

  f4 acc[MT][4] = {};

  auto STAGE = [&](int buf, int kk) {
    int k0 = kk * 64;
#pragma unroll
    for (int i = 0; i < 4; i++) {                // A: 16 chunks of 8 rows
      int c = i * 4 + w;
      int row = c * 8 + (lane >> 3);
      int col = ((lane & 7) * 8) ^ ((row & 7) << 3);
      gl2lds16(A + (size_t)(m0 + row) * K + k0 + col, smem + buf * 16384 + c * 1024);
    }
#pragma unroll
    for (int i = 0; i < BN / 32; i++) {          // B: BN/8 chunks of 8 rows
      int c = i * 4 + w;
      int row = c * 8 + (lane >> 3);
      int col = ((lane & 7) * 8) ^ ((row & 7) << 3);
      gl2lds16(Bt + (size_t)(n0 + row) * K + k0 + col, smem + 32768 + buf * BB + c * 1024);
    }
  };

  const int nk = K / 64;
  STAGE(0, 0);
  STAGE(1, 1);

  for (int kk = 0; kk < nk; kk++) {
    if (kk + 1 < nk) {
      if constexpr (BN == 128) { asm volatile("s_waitcnt vmcnt(8)" ::: "memory"); }
      else                     { asm volatile("s_waitcnt vmcnt(6)" ::: "memory"); }
    } else {
      asm volatile("s_waitcnt vmcnt(0)" ::: "memory");
    }
    __builtin_amdgcn_s_barrier();                // buf[kk&1] ready for all waves

    const char* Al = smem + (kk & 1) * 16384;
    const char* Bl = smem + 32768 + (kk & 1) * BB;
    __builtin_amdgcn_s_setprio(1);
#pragma unroll
    for (int ks = 0; ks < 2; ks++) {
      bf8 af[MT], bfr[4];
#pragma unroll
      for (int mt = 0; mt < MT; mt++) {
        int rr = wm * (MT * 16) + mt * 16 + (lane & 15);
        af[mt] = *(const bf8*)(Al + rr * 128 + ((ks * 64 + (lane >> 4) * 16) ^ ((rr & 7) << 4)));
      }
#pragma unroll
      for (int nt = 0; nt < 4; nt++) {
        int rr = wn * 64 + nt * 16 + (lane & 15);
        bfr[nt] = *(const bf8*)(Bl + rr * 128 + ((ks * 64 + (lane >> 4) * 16) ^ ((rr & 7) << 4)));
      }
#pragma unroll
      for (int mt = 0; mt < MT; mt++)
#pragma unroll
        for (int nt = 0; nt < 4; nt++)
          acc[mt][nt] = __builtin_amdgcn_mfma_f32_16x16x32_bf16(af[mt], bfr[nt], acc[mt][nt], 0, 0, 0);
    }
    __builtin_amdgcn_s_setprio(0);

    __builtin_amdgcn_s_barrier();                // all waves done reading buf[kk&1]
    if (kk + 2 < nk) STAGE(kk & 1, kk + 2);      // overwrite with tile kk+2
  }

  if (MODE == 0) {
    const int region = n0 >> 10;
    if (region < 2) {
      float sc = (region == 0) ? 0.180336880f : 1.0f;
#pragma unroll
      for (int nt = 0; nt < 4; nt++) {
        int n = n0 + wn * 64 + nt * 16 + (lane & 15);
        float bv = bias[n];
        int c = n & 1023, h = c >> 6, d = c & 63;
#pragma unroll
        for (int mt = 0; mt < MT; mt++) {
#pragma unroll
          for (int r = 0; r < 4; r++) {
            int m = m0 + wm * (MT * 16) + mt * 16 + (lane >> 4) * 4 + r;
            int b = m >> 11, t = m & 2047;
            size_t off = ((((size_t)region * 2 + b) * 16 + h) * 2048 + t) * 64 + d;
            Oq[off] = bfbits((acc[mt][nt][r] + bv) * sc);
          }
        }
      }
    } else {
#pragma unroll
      for (int nt = 0; nt < 4; nt++) {
        int n = n0 + wn * 64 + nt * 16 + (lane & 15);
        float bv = bias[n];
        int c = n & 1023, h = c >> 6, d = c & 63;
#pragma unroll
        for (int mt = 0; mt < MT; mt++) {
          int m = m0 + wm * (MT * 16) + mt * 16 + (lane >> 4) * 4;
          int b = m >> 11, t = m & 2047;
          size_t off = (((size_t)b * 16 + h) * 64 + d) * 2048 + t;
          u16x4 pk4;
#pragma unroll
          for (int r = 0; r < 4; r++) pk4[r] = bfbits(acc[mt][nt][r] + bv);
          *(u16x4*)(Ov + off) = pk4;
        }
      }
    }
  } else {
#pragma unroll
    for (int mt = 0; mt < MT; mt++) {
#pragma unroll
      for (int r = 0; r < 4; r++) {
        int m = m0 + wm * (MT * 16) + mt * 16 + (lane >> 4) * 4 + r;
#pragma unroll
        for (int nt = 0; nt < 4; nt++) {
          int n = n0 + wn * 64 + nt * 16 + (lane & 15);
          Of[(size_t)m * N + n] = acc[mt][nt][r] + bias[n];
        }
      }
    }
  }
}

// ---------------- causal flash attention v12 (frozen best) ----------------
__global__ __launch_bounds__(256) void attn12(const unsigned short* __restrict__ Qb,
                                              const unsigned short* __restrict__ Kb,
                                              const unsigned short* __restrict__ Vtb,
                                              unsigned short* __restrict__ Ob,
                                              unsigned short* __restrict__ partO,
                                              float* __restrict__ Lbuf) {
  static const signed char QTs[32] = {15,15,14,14,13,13,12,12,11,11,10,10,9,8,7,6,5,15,4,9,14,3,8,13,2,7,12,1,6,11,0,5};
  static const signed char TSs[32] = {0,11,0,11,0,11,0,11,0,11,0,11,0,0,0,0,0,22,0,11,22,0,11,22,0,11,22,0,11,22,0,11};
  static const signed char PS[32]  = {0,1,2,3,4,5,6,7,8,9,10,11,12,13,14,15,16,17,-1,18,19,-1,20,21,-1,22,23,-1,24,25,-1,26};
  const int idx = blockIdx.x;
  const int s = idx >> 5, bh = idx & 31;
  const int qt = QTs[s], ts = TSs[s];
  const int ntot = 2 * qt + 2;
  const int te = min(ts + 11, ntot);
  const int slot = PS[s];                        // -1 => direct store

  const int tid = threadIdx.x;
  const int w = tid >> 6, lane = tid & 63;
  const int hi = lane >> 5, q32 = lane & 31;

  __shared__ char smem[49152];                   // K tri-buf 3x8K | Vt tri-buf 3x8K at +24576

  const unsigned short* Qg  = Qb  + (size_t)bh * SEQ * HD;
  const unsigned short* Kg  = Kb  + (size_t)bh * SEQ * HD;
  const unsigned short* Vtg = Vtb + (size_t)bh * SEQ * HD;  // [64 d][2048 t]

  const int qbw  = qt * 128 + w * 32;            // wave's first q-row
  const int qrow = qbw + q32;                    // this lane's q-row (S/P col)

  bf8 qf[4];                                     // Q[qrow][kc*16 + hi*8 + e]
#pragma unroll
  for (int kc = 0; kc < 4; kc++)
    qf[kc] = *(const bf8*)(Qg + (size_t)qrow * HD + kc * 16 + hi * 8);

  f16v acc0 = {}, acc1 = {};                     // O[q][d], d-blocks 0..31 / 32..63
  float lr = 0.f;                                // per-lane partial row-sum

  auto STAGE = [&](int buf, int t) {
    int kv0 = t * 64;
#pragma unroll
    for (int i = 0; i < 2; i++) {
      int c = i * 4 + w;                         // 8 chunks of 8 rows, split across 4 waves
      int row = c * 8 + (lane >> 3);
      int col = ((lane & 7) * 8) ^ ((row & 7) << 3);   // pre-swizzled source
      gl2lds16(Kg + (size_t)(kv0 + row) * HD + col,    smem + buf * 8192 + c * 1024);
      gl2lds16(Vtg + (size_t)row * SEQ + kv0 + col,    smem + 24576 + buf * 8192 + c * 1024);
    }
  };

  const int nt_loc = te - ts;
  STAGE(0, ts);                                  // 2-deep prefetch prologue
  if (nt_loc > 1) STAGE(1, ts + 1);

  for (int tl = 0; tl < nt_loc; tl++) {
    const int t = ts + tl;
    const int kv0 = t * 64;

    if (tl + 1 < nt_loc) {
      asm volatile("s_waitcnt vmcnt(4)" ::: "memory");
    } else {
      asm volatile("s_waitcnt vmcnt(0)" ::: "memory");
    }
    __builtin_amdgcn_s_barrier();                // single barrier: tile tl ready everywhere
    if (tl + 2 < nt_loc) STAGE((tl + 2) % 3, t + 2);   // issue early; hides under compute

    if (kv0 <= qbw + 31) {                       // wave-uniform: skip fully-masked tiles
      const char* kl = smem + (tl % 3) * 8192;
      const char* vl = smem + 24576 + (tl % 3) * 8192;
      const bool hi_vis = (kv0 + 32 <= qbw + 31);  // upper key-half visible?

      // S^T = K Q^T (zero C-init; softmax is shift-invariant)
      f16v s0 = {}, s1 = {};
      __builtin_amdgcn_s_setprio(1);
#pragma unroll
      for (int kc = 0; kc < 4; kc++) {
        int r0 = q32;
        bf8 k0 = *(const bf8*)(kl + r0 * 128 + ((kc * 32 + hi * 16) ^ ((r0 & 7) << 4)));
        s0 = __builtin_amdgcn_mfma_f32_32x32x16_bf16(k0, qf[kc], s0, 0, 0, 0);
      }
      if (hi_vis) {
#pragma unroll
        for (int kc = 0; kc < 4; kc++) {
          int r1 = 32 + q32;
          bf8 k1 = *(const bf8*)(kl + r1 * 128 + ((kc * 32 + hi * 16) ^ ((r1 & 7) << 4)));
          s1 = __builtin_amdgcn_mfma_f32_32x32x16_bf16(k1, qf[kc], s1, 0, 0, 0);
        }
      }
      __builtin_amdgcn_s_setprio(0);

      if (kv0 + 63 > qbw) {                      // diagonal overlap: mask
#pragma unroll
        for (int r = 0; r < 16; r++) {
          int key = kv0 + (r & 3) + 8 * (r >> 2) + 4 * hi;
          if (key > qrow)      s0[r] = -1e30f;
          if (key + 32 > qrow) s1[r] = -1e30f;
        }
      }

      // P = exp2(S) -> packed bf16 words; l accumulates per-lane (lane-local q-row)
      uint32_t u[16];
#pragma unroll
      for (int m8 = 0; m8 < 8; m8++) {
        float pa = fexp2(s0[2 * m8]), pb = fexp2(s0[2 * m8 + 1]);
        lr += pa + pb;
        u[m8] = pk_bf16(pa, pb);
      }
      if (hi_vis) {
#pragma unroll
        for (int m8 = 0; m8 < 8; m8++) {
          float pc = fexp2(s1[2 * m8]), pd = fexp2(s1[2 * m8 + 1]);
          lr += pc + pd;
          u[8 + m8] = pk_bf16(pc, pd);
        }
      }

      // O += P V  (A-frag via permlane32_swap, no selects)
      __builtin_amdgcn_s_setprio(1);
      const int ncc = hi_vis ? 4 : 2;
      for (int kcc = 0; kcc < ncc; kcc++) {
        const int base = (kcc >> 1) * 8 + (kcc & 1) * 4;
        uint32_t a0 = u[base + 0], a2 = u[base + 2];
        uint32_t a1 = u[base + 1], a3 = u[base + 3];
        asm("v_permlane32_swap_b32 %0, %1" : "+v"(a0), "+v"(a2));
        asm("v_permlane32_swap_b32 %0, %1" : "+v"(a1), "+v"(a3));
        U4 f; f.u[0] = a0; f.u[1] = a1; f.u[2] = a2; f.u[3] = a3;
        int r0 = q32, r1 = 32 + q32;
        bf8 v0 = *(const bf8*)(vl + r0 * 128 + ((kcc * 32 + hi * 16) ^ ((r0 & 7) << 4)));
        bf8 v1 = *(const bf8*)(vl + r1 * 128 + ((kcc * 32 + hi * 16) ^ ((r1 & 7) << 4)));
        acc0 = __builtin_amdgcn_mfma_f32_32x32x16_bf16(f.v, v0, acc0, 0, 0, 0);
        acc1 = __builtin_amdgcn_mfma_f32_32x32x16_bf16(f.v, v1, acc1, 0, 0, 0);
      }
      __builtin_amdgcn_s_setprio(0);
    }
  }

  // finalize: total l per q-row = lr(hi=0) + lr(hi=1); lane q32 owns q-row q32.
  lr += __shfl_xor(lr, 32);
  if (slot < 0) {                                // single segment: normalize + store
    int b = bh >> 4, h = bh & 15;
    unsigned short* Og = Ob + (size_t)b * SEQ * EMBED;
#pragma unroll
    for (int r = 0; r < 16; r++) {
      int ql_ = (r & 3) + 8 * (r >> 2) + 4 * hi;
      float linv = frcp(__shfl(lr, ql_));
      size_t rowoff = (size_t)(qbw + ql_) * EMBED + h * 64;
      Og[rowoff + q32]      = bfbits(acc0[r] * linv);
      Og[rowoff + 32 + q32] = bfbits(acc1[r] * linv);
    }
  } else {                                       // partial: unnormalized bf16 O + l
    int pidx = slot * 32 + bh;
    unsigned short* P0 = partO + (size_t)pidx * 8192;   // [128 q][64 d]
#pragma unroll
    for (int r = 0; r < 16; r++) {
      int ql_ = (r & 3) + 8 * (r >> 2) + 4 * hi;
      int rowl = w * 32 + ql_;
      P0[rowl * 64 + q32]      = bfbits(acc0[r]);
      P0[rowl * 64 + 32 + q32] = bfbits(acc1[r]);
    }
    if (hi == 0) Lbuf[pidx * 128 + w * 32 + q32] = lr;   // lanes 0..31: one row each
  }
}

// ---------------- combine 2..3 KV-segments (linear merge) ----------------
__global__ __launch_bounds__(256) void attn_combine(const unsigned short* __restrict__ partO,
                                                    const float* __restrict__ Lbuf,
                                                    unsigned short* __restrict__ Ob) {
  static const signed char NSg[11] = {2,2,2,2,2,2,3,3,3,3,3};              // qt = 5..15
  static const signed char SL[11][3] = {
    {16,26,0},{15,24,0},{14,22,0},{13,20,0},{12,18,0},{10,11,0},
    {8,9,25},{6,7,23},{4,5,21},{2,3,19},{0,1,17}};
  int pair = blockIdx.x;                 // (qt-5)*32 + bh
  int qi = pair >> 5, bh = pair & 31;
  int qt = 5 + qi;
  int ns = NSg[qi];
  int b = bh >> 4, h = bh & 15;
#pragma unroll
  for (int rr = 0; rr < 2; rr++) {
    int row = rr * 64 + (threadIdx.x >> 2);   // 0..127
    int d0 = (threadIdx.x & 3) * 16;          // 16 d-elems per thread
    float lsum = 0.f;
    float acc[16] = {};
    for (int sg = 0; sg < ns; sg++) {
      int pidx = (int)SL[qi][sg] * 32 + bh;
      lsum += Lbuf[pidx * 128 + row];
      const unsigned short* O0 = partO + (size_t)pidx * 8192 + row * 64 + d0;
#pragma unroll
      for (int v = 0; v < 4; v++) {
        u16x4 a = *(const u16x4*)(O0 + v * 4);
#pragma unroll
        for (int e = 0; e < 4; e++) acc[v * 4 + e] += bf2f(a[e]);
      }
    }
    float linv = 1.f / lsum;
    unsigned short* out = Ob + ((size_t)b * SEQ + qt * 128 + row) * EMBED + h * 64 + d0;
    u16x4 res[4];
#pragma unroll
    for (int v = 0; v < 4; v++) {
#pragma unroll
      for (int e = 0; e < 4; e++) res[v][e] = bfbits(acc[v * 4 + e] * linv);
    }
    *(u16x4*)(out)      = res[0];
    *(u16x4*)(out + 4)  = res[1];
    *(u16x4*)(out + 8)  = res[2];
    *(u16x4*)(out + 12) = res[3];
  }
}

extern "C" void kernel_launch(void* const* d_in, const int* in_sizes, int n_in,
                              void* d_out, int out_size, void* d_ws, size_t ws_size,
                              hipStream_t stream) {
  const float* x    = (const float*)d_in[0];
  const float* Wqkv = (const float*)d_in[1];
  const float* bqkv = (const float*)d_in[2];
  const float* Wout = (const float*)d_in[3];
  const float* bout = (const float*)d_in[4];
  float* out = (float*)d_out;

  char* ws = (char*)d_ws;
  unsigned short* xb    = (unsigned short*)ws;
  unsigned short* wqkvT = (unsigned short*)(ws + (size_t)8 * 1048576);
  unsigned short* partO = (unsigned short*)ws;
  float*          lbuf  = (float*)(ws + 14155776);
  unsigned short* woutT = (unsigned short*)(ws + (size_t)14 * 1048576); // 2 MB (live for gemm2)
  unsigned short* qk    = (unsigned short*)(ws + (size_t)16 * 1048576); // 16 MB [2][B][H][T][D]
  unsigned short* vT    = (unsigned short*)(ws + (size_t)32 * 1048576); // 8 MB  [B*H][D][T]
  unsigned short* obuf  = (unsigned short*)(ws + (size_t)40 * 1048576); // 8 MB  [B][T][C]

  prep<<<dim3(4096 + 768 + 256), 256, 0, stream>>>(x, xb, Wqkv, wqkvT, Wout, woutT);

  gemm8<<<dim3(12, 16), 512, 0, stream>>>(xb, wqkvT, bqkv, qk, vT, MTOK, 3 * EMBED, EMBED);

  const unsigned short* Qb = qk;
  const unsigned short* Kb = qk + (size_t)BATCH * NH * SEQ * HD;
  attn12<<<dim3(32 * 32), 256, 0, stream>>>(Qb, Kb, vT, obuf, partO, lbuf);
  attn_combine<<<dim3(11 * 32), 256, 0, stream>>>(partO, lbuf, obuf);

  gemm_bt<128, 1><<<dim3(8, 32), 256, 0, stream>>>(obuf, woutT, bout, nullptr, nullptr, out,
                                                   MTOK, EMBED, EMBED);
}

// Round 19
// 104.394 us; speedup vs baseline: 1.0510x; 1.0510x over previous
//
#include <hip/hip_runtime.h>
#include <hip/hip_bf16.h>
#include <stdint.h>

#define EMBED 1024
#define NH 16
#define HD 64
#define BATCH 2
#define SEQ 2048
#define MTOK (BATCH*SEQ)   // 4096

using bf8 = __attribute__((ext_vector_type(8))) short;     // 8 bf16 = one MFMA A/B frag
using f4  = __attribute__((ext_vector_type(4))) float;     // 16x16 C/D frag
using f16v = __attribute__((ext_vector_type(16))) float;   // 32x32 C/D frag
using u16x4 = __attribute__((ext_vector_type(4))) unsigned short;

union U4 { uint32_t u[4]; bf8 v; };

__device__ __forceinline__ uint32_t pk_bf16(float a, float b) {
  __hip_bfloat162 h = __float22bfloat162_rn(float2{a, b});
  union { __hip_bfloat162 h; uint32_t u; } c; c.h = h; return c.u;
}
__device__ __forceinline__ unsigned short bfbits(float f) {
  __hip_bfloat16 h = __float2bfloat16(f);
  union { __hip_bfloat16 h; unsigned short u; } c; c.h = h; return c.u;
}
__device__ __forceinline__ float bf2f(unsigned short u) {
  union { uint32_t u; float f; } c; c.u = (uint32_t)u << 16; return c.f;
}
__device__ __forceinline__ float fexp2(float x) {
#if __has_builtin(__builtin_amdgcn_exp2f)
  return __builtin_amdgcn_exp2f(x);
#else
  return exp2f(x);
#endif
}
__device__ __forceinline__ float frcp(float x) {
#if __has_builtin(__builtin_amdgcn_rcpf)
  return __builtin_amdgcn_rcpf(x);
#else
  return 1.f / x;
#endif
}

__device__ __forceinline__ void gl2lds16(const void* g, void* l) {
  __builtin_amdgcn_global_load_lds(
      (const __attribute__((address_space(1))) void*)g,
      (__attribute__((address_space(3))) void*)l, 16, 0, 0);
}

// ---------------- fused prep: x->bf16 | Wqkv transpose | Wout transpose ----------------
__global__ __launch_bounds__(256) void prep(const float* __restrict__ x,
                                            unsigned short* __restrict__ xb,
                                            const float* __restrict__ Wqkv,
                                            unsigned short* __restrict__ wqkvT,
                                            const float* __restrict__ Wout,
                                            unsigned short* __restrict__ woutT) {
  __shared__ float tl[64][65];
  int blk = blockIdx.x;
  if (blk < 4096) {                              // fp32 -> bf16, 1024 elems/block
    int i = (blk * 256 + threadIdx.x) * 4;
    float4 v = *(const float4*)(x + i);
    uint2 o;
    o.x = pk_bf16(v.x, v.y);
    o.y = pk_bf16(v.z, v.w);
    *(uint2*)(xb + i) = o;
    return;
  }
  const float* W; unsigned short* Wt; int K, N, bx, by;
  if (blk < 4096 + 768) {
    int j = blk - 4096; W = Wqkv; Wt = wqkvT; K = 1024; N = 3072;
    bx = j % 48; by = j / 48;
  } else {
    int j = blk - 4096 - 768; W = Wout; Wt = woutT; K = 1024; N = 1024;
    bx = j % 16; by = j / 16;
  }
  int k0 = by * 64, n0 = bx * 64;
  int tr = threadIdx.x >> 6, tc = threadIdx.x & 63;
#pragma unroll
  for (int i = 0; i < 16; i++) {
    int r = tr + i * 4;
    tl[r][tc] = W[(size_t)(k0 + r) * N + n0 + tc];
  }
  __syncthreads();
#pragma unroll
  for (int i = 0; i < 16; i++) {
    int r = tr + i * 4;
    Wt[(size_t)(n0 + r) * K + k0 + tc] = bfbits(tl[tc][r]);
  }
}

// ---------------- pipelined bf16 GEMM: C[M][N] = A[M][K]*Bt[N][K]^T + bias ----------------
// BM=128, BN in {64,128}, BK=64, double-buffered LDS, counted-vmcnt schedule:
// prologue stages 2 K-tiles; per iter [vmcnt(N); s_barrier] -> ds_read+MFMA ->
// [s_barrier] -> STAGE(k+2). N = loads/thread/stage = 4 + BN/32.
template<int BN, int MODE>
__global__ __launch_bounds__(256) void gemm_bt(const unsigned short* __restrict__ A,
                                               const unsigned short* __restrict__ Bt,
                                               const float* __restrict__ bias,
                                               unsigned short* __restrict__ Oq,
                                               unsigned short* __restrict__ Ov,
                                               float* __restrict__ Of,
                                               int M, int N, int K) {
  constexpr int MT = (BN == 128) ? 4 : 2;
  constexpr int BB = BN * 128;                   // bytes per B buffer
  const int tid = threadIdx.x;
  const int w = tid >> 6, lane = tid & 63;
  const int wm = (BN == 128) ? (w >> 1) : w;
  const int wn = (BN == 128) ? (w & 1) : 0;
  const int m0 = blockIdx.y * 128, n0 = blockIdx.x * BN;

  __shared__ char smem[32768 + 2 * BB];          // A dbuf 2x16K | B dbuf 2xBB

  f4 acc[MT][4] = {};

  auto STAGE = [&](int buf, int kk) {
    int k0 = kk * 64;
#pragma unroll
    for (int i = 0; i < 4; i++) {                // A: 16 chunks of 8 rows
      int c = i * 4 + w;
      int row = c * 8 + (lane >> 3);
      int col = ((lane & 7) * 8) ^ ((row & 7) << 3);
      gl2lds16(A + (size_t)(m0 + row) * K + k0 + col, smem + buf * 16384 + c * 1024);
    }
#pragma unroll
    for (int i = 0; i < BN / 32; i++) {          // B: BN/8 chunks of 8 rows
      int c = i * 4 + w;
      int row = c * 8 + (lane >> 3);
      int col = ((lane & 7) * 8) ^ ((row & 7) << 3);
      gl2lds16(Bt + (size_t)(n0 + row) * K + k0 + col, smem + 32768 + buf * BB + c * 1024);
    }
  };

  const int nk = K / 64;
  STAGE(0, 0);
  STAGE(1, 1);

  for (int kk = 0; kk < nk; kk++) {
    if (kk + 1 < nk) {
      if constexpr (BN == 128) { asm volatile("s_waitcnt vmcnt(8)" ::: "memory"); }
      else                     { asm volatile("s_waitcnt vmcnt(6)" ::: "memory"); }
    } else {
      asm volatile("s_waitcnt vmcnt(0)" ::: "memory");
    }
    __builtin_amdgcn_s_barrier();                // buf[kk&1] ready for all waves

    const char* Al = smem + (kk & 1) * 16384;
    const char* Bl = smem + 32768 + (kk & 1) * BB;
    __builtin_amdgcn_s_setprio(1);
#pragma unroll
    for (int ks = 0; ks < 2; ks++) {
      bf8 af[MT], bfr[4];
#pragma unroll
      for (int mt = 0; mt < MT; mt++) {
        int rr = wm * (MT * 16) + mt * 16 + (lane & 15);
        af[mt] = *(const bf8*)(Al + rr * 128 + ((ks * 64 + (lane >> 4) * 16) ^ ((rr & 7) << 4)));
      }
#pragma unroll
      for (int nt = 0; nt < 4; nt++) {
        int rr = wn * 64 + nt * 16 + (lane & 15);
        bfr[nt] = *(const bf8*)(Bl + rr * 128 + ((ks * 64 + (lane >> 4) * 16) ^ ((rr & 7) << 4)));
      }
#pragma unroll
      for (int mt = 0; mt < MT; mt++)
#pragma unroll
        for (int nt = 0; nt < 4; nt++)
          acc[mt][nt] = __builtin_amdgcn_mfma_f32_16x16x32_bf16(af[mt], bfr[nt], acc[mt][nt], 0, 0, 0);
    }
    __builtin_amdgcn_s_setprio(0);

    __builtin_amdgcn_s_barrier();                // all waves done reading buf[kk&1]
    if (kk + 2 < nk) STAGE(kk & 1, kk + 2);      // overwrite with tile kk+2
  }

  if (MODE == 0) {
    const int region = n0 >> 10;                 // uniform across block
    if (region < 2) {                            // Q or K scatter
      float sc = (region == 0) ? 0.180336880f : 1.0f;  // 1/8 * log2(e) folded into Q
#pragma unroll
      for (int nt = 0; nt < 4; nt++) {
        int n = n0 + wn * 64 + nt * 16 + (lane & 15);
        float bv = bias[n];
        int c = n & 1023, h = c >> 6, d = c & 63;
#pragma unroll
        for (int mt = 0; mt < MT; mt++) {
#pragma unroll
          for (int r = 0; r < 4; r++) {
            int m = m0 + wm * (MT * 16) + mt * 16 + (lane >> 4) * 4 + r;
            int b = m >> 11, t = m & 2047;
            size_t off = ((((size_t)region * 2 + b) * 16 + h) * 2048 + t) * 64 + d;
            Oq[off] = bfbits((acc[mt][nt][r] + bv) * sc);
          }
        }
      }
    } else {                                     // V transposed, t-contiguous b64
#pragma unroll
      for (int nt = 0; nt < 4; nt++) {
        int n = n0 + wn * 64 + nt * 16 + (lane & 15);
        float bv = bias[n];
        int c = n & 1023, h = c >> 6, d = c & 63;
#pragma unroll
        for (int mt = 0; mt < MT; mt++) {
          int m = m0 + wm * (MT * 16) + mt * 16 + (lane >> 4) * 4;
          int b = m >> 11, t = m & 2047;
          size_t off = (((size_t)b * 16 + h) * 64 + d) * 2048 + t;
          u16x4 pk4;
#pragma unroll
          for (int r = 0; r < 4; r++) pk4[r] = bfbits(acc[mt][nt][r] + bv);
          *(u16x4*)(Ov + off) = pk4;
        }
      }
    }
  } else {
#pragma unroll
    for (int mt = 0; mt < MT; mt++) {
#pragma unroll
      for (int r = 0; r < 4; r++) {
        int m = m0 + wm * (MT * 16) + mt * 16 + (lane >> 4) * 4 + r;
#pragma unroll
        for (int nt = 0; nt < 4; nt++) {
          int n = n0 + wn * 64 + nt * 16 + (lane & 15);
          Of[(size_t)m * N + n] = acc[mt][nt][r] + bias[n];
        }
      }
    }
  }
}

// ---------------- causal flash attention v12: triple-buffer, ONE barrier/tile ----------------
// (best measured. 4 waves x 32 q-rows, KVBLK=64, swapped 32x32 QK^T,
// in-register P, per-lane l, counted-vmcnt, mod-3 LDS buffers.)
__global__ __launch_bounds__(256) void attn12(const unsigned short* __restrict__ Qb,
                                              const unsigned short* __restrict__ Kb,
                                              const unsigned short* __restrict__ Vtb,
                                              unsigned short* __restrict__ Ob,
                                              unsigned short* __restrict__ partO,
                                              float* __restrict__ Lbuf) {
  static const signed char QTs[32] = {15,15,14,14,13,13,12,12,11,11,10,10,9,8,7,6,5,15,4,9,14,3,8,13,2,7,12,1,6,11,0,5};
  static const signed char TSs[32] = {0,11,0,11,0,11,0,11,0,11,0,11,0,0,0,0,0,22,0,11,22,0,11,22,0,11,22,0,11,22,0,11};
  static const signed char PS[32]  = {0,1,2,3,4,5,6,7,8,9,10,11,12,13,14,15,16,17,-1,18,19,-1,20,21,-1,22,23,-1,24,25,-1,26};
  const int idx = blockIdx.x;
  const int s = idx >> 5, bh = idx & 31;
  const int qt = QTs[s], ts = TSs[s];
  const int ntot = 2 * qt + 2;
  const int te = min(ts + 11, ntot);
  const int slot = PS[s];                        // -1 => direct store

  const int tid = threadIdx.x;
  const int w = tid >> 6, lane = tid & 63;
  const int hi = lane >> 5, q32 = lane & 31;

  __shared__ char smem[49152];                   // K tri-buf 3x8K | Vt tri-buf 3x8K at +24576

  const unsigned short* Qg  = Qb  + (size_t)bh * SEQ * HD;
  const unsigned short* Kg  = Kb  + (size_t)bh * SEQ * HD;
  const unsigned short* Vtg = Vtb + (size_t)bh * SEQ * HD;  // [64 d][2048 t]

  const int qbw  = qt * 128 + w * 32;            // wave's first q-row
  const int qrow = qbw + q32;                    // this lane's q-row (S/P col)

  bf8 qf[4];                                     // Q[qrow][kc*16 + hi*8 + e]
#pragma unroll
  for (int kc = 0; kc < 4; kc++)
    qf[kc] = *(const bf8*)(Qg + (size_t)qrow * HD + kc * 16 + hi * 8);

  f16v acc0 = {}, acc1 = {};                     // O[q][d], d-blocks 0..31 / 32..63
  float lr = 0.f;                                // per-lane partial row-sum

  auto STAGE = [&](int buf, int t) {
    int kv0 = t * 64;
#pragma unroll
    for (int i = 0; i < 2; i++) {
      int c = i * 4 + w;                         // 8 chunks of 8 rows, split across 4 waves
      int row = c * 8 + (lane >> 3);
      int col = ((lane & 7) * 8) ^ ((row & 7) << 3);   // pre-swizzled source
      gl2lds16(Kg + (size_t)(kv0 + row) * HD + col,    smem + buf * 8192 + c * 1024);
      gl2lds16(Vtg + (size_t)row * SEQ + kv0 + col,    smem + 24576 + buf * 8192 + c * 1024);
    }
  };

  const int nt_loc = te - ts;
  STAGE(0, ts);                                  // 2-deep prefetch prologue
  if (nt_loc > 1) STAGE(1, ts + 1);

  for (int tl = 0; tl < nt_loc; tl++) {
    const int t = ts + tl;
    const int kv0 = t * 64;

    if (tl + 1 < nt_loc) {
      asm volatile("s_waitcnt vmcnt(4)" ::: "memory");
    } else {
      asm volatile("s_waitcnt vmcnt(0)" ::: "memory");
    }
    __builtin_amdgcn_s_barrier();                // single barrier: tile tl ready everywhere
    if (tl + 2 < nt_loc) STAGE((tl + 2) % 3, t + 2);   // issue early; hides under compute

    if (kv0 <= qbw + 31) {                       // wave-uniform: skip fully-masked tiles
      const char* kl = smem + (tl % 3) * 8192;
      const char* vl = smem + 24576 + (tl % 3) * 8192;
      const bool hi_vis = (kv0 + 32 <= qbw + 31);  // upper key-half visible?

      // S^T = K Q^T (zero C-init; softmax is shift-invariant)
      f16v s0 = {}, s1 = {};
      __builtin_amdgcn_s_setprio(1);
#pragma unroll
      for (int kc = 0; kc < 4; kc++) {
        int r0 = q32;
        bf8 k0 = *(const bf8*)(kl + r0 * 128 + ((kc * 32 + hi * 16) ^ ((r0 & 7) << 4)));
        s0 = __builtin_amdgcn_mfma_f32_32x32x16_bf16(k0, qf[kc], s0, 0, 0, 0);
      }
      if (hi_vis) {
#pragma unroll
        for (int kc = 0; kc < 4; kc++) {
          int r1 = 32 + q32;
          bf8 k1 = *(const bf8*)(kl + r1 * 128 + ((kc * 32 + hi * 16) ^ ((r1 & 7) << 4)));
          s1 = __builtin_amdgcn_mfma_f32_32x32x16_bf16(k1, qf[kc], s1, 0, 0, 0);
        }
      }
      __builtin_amdgcn_s_setprio(0);

      if (kv0 + 63 > qbw) {                      // diagonal overlap: mask
#pragma unroll
        for (int r = 0; r < 16; r++) {
          int key = kv0 + (r & 3) + 8 * (r >> 2) + 4 * hi;
          if (key > qrow)      s0[r] = -1e30f;
          if (key + 32 > qrow) s1[r] = -1e30f;
        }
      }

      // P = exp2(S) -> packed bf16 words; l accumulates per-lane (lane-local q-row)
      uint32_t u[16];
#pragma unroll
      for (int m8 = 0; m8 < 8; m8++) {
        float pa = fexp2(s0[2 * m8]), pb = fexp2(s0[2 * m8 + 1]);
        lr += pa + pb;
        u[m8] = pk_bf16(pa, pb);
      }
      if (hi_vis) {
#pragma unroll
        for (int m8 = 0; m8 < 8; m8++) {
          float pc = fexp2(s1[2 * m8]), pd = fexp2(s1[2 * m8 + 1]);
          lr += pc + pd;
          u[8 + m8] = pk_bf16(pc, pd);
        }
      }

      // O += P V  (A-frag via permlane32_swap, no selects)
      __builtin_amdgcn_s_setprio(1);
      const int ncc = hi_vis ? 4 : 2;
      for (int kcc = 0; kcc < ncc; kcc++) {
        const int base = (kcc >> 1) * 8 + (kcc & 1) * 4;
        uint32_t a0 = u[base + 0], a2 = u[base + 2];
        uint32_t a1 = u[base + 1], a3 = u[base + 3];
        asm("v_permlane32_swap_b32 %0, %1" : "+v"(a0), "+v"(a2));
        asm("v_permlane32_swap_b32 %0, %1" : "+v"(a1), "+v"(a3));
        U4 f; f.u[0] = a0; f.u[1] = a1; f.u[2] = a2; f.u[3] = a3;
        int r0 = q32, r1 = 32 + q32;
        bf8 v0 = *(const bf8*)(vl + r0 * 128 + ((kcc * 32 + hi * 16) ^ ((r0 & 7) << 4)));
        bf8 v1 = *(const bf8*)(vl + r1 * 128 + ((kcc * 32 + hi * 16) ^ ((r1 & 7) << 4)));
        acc0 = __builtin_amdgcn_mfma_f32_32x32x16_bf16(f.v, v0, acc0, 0, 0, 0);
        acc1 = __builtin_amdgcn_mfma_f32_32x32x16_bf16(f.v, v1, acc1, 0, 0, 0);
      }
      __builtin_amdgcn_s_setprio(0);
    }
  }

  // finalize: total l per q-row = lr(hi=0) + lr(hi=1); lane q32 owns q-row q32.
  lr += __shfl_xor(lr, 32);
  if (slot < 0) {                                // single segment: normalize + store
    int b = bh >> 4, h = bh & 15;
    unsigned short* Og = Ob + (size_t)b * SEQ * EMBED;
#pragma unroll
    for (int r = 0; r < 16; r++) {
      int ql_ = (r & 3) + 8 * (r >> 2) + 4 * hi;
      float linv = frcp(__shfl(lr, ql_));
      size_t rowoff = (size_t)(qbw + ql_) * EMBED + h * 64;
      Og[rowoff + q32]      = bfbits(acc0[r] * linv);
      Og[rowoff + 32 + q32] = bfbits(acc1[r] * linv);
    }
  } else {                                       // partial: unnormalized bf16 O + l
    int pidx = slot * 32 + bh;
    unsigned short* P0 = partO + (size_t)pidx * 8192;   // [128 q][64 d]
#pragma unroll
    for (int r = 0; r < 16; r++) {
      int ql_ = (r & 3) + 8 * (r >> 2) + 4 * hi;
      int rowl = w * 32 + ql_;
      P0[rowl * 64 + q32]      = bfbits(acc0[r]);
      P0[rowl * 64 + 32 + q32] = bfbits(acc1[r]);
    }
    if (hi == 0) Lbuf[pidx * 128 + w * 32 + q32] = lr;   // lanes 0..31: one row each
  }
}

// ---------------- combine 2..3 KV-segments (linear merge) ----------------
__global__ __launch_bounds__(256) void attn_combine(const unsigned short* __restrict__ partO,
                                                    const float* __restrict__ Lbuf,
                                                    unsigned short* __restrict__ Ob) {
  static const signed char NSg[11] = {2,2,2,2,2,2,3,3,3,3,3};              // qt = 5..15
  static const signed char SL[11][3] = {
    {16,26,0},{15,24,0},{14,22,0},{13,20,0},{12,18,0},{10,11,0},
    {8,9,25},{6,7,23},{4,5,21},{2,3,19},{0,1,17}};
  int pair = blockIdx.x;                 // (qt-5)*32 + bh
  int qi = pair >> 5, bh = pair & 31;
  int qt = 5 + qi;
  int ns = NSg[qi];
  int b = bh >> 4, h = bh & 15;
#pragma unroll
  for (int rr = 0; rr < 2; rr++) {
    int row = rr * 64 + (threadIdx.x >> 2);   // 0..127
    int d0 = (threadIdx.x & 3) * 16;          // 16 d-elems per thread
    float lsum = 0.f;
    float acc[16] = {};
    for (int sg = 0; sg < ns; sg++) {
      int pidx = (int)SL[qi][sg] * 32 + bh;
      lsum += Lbuf[pidx * 128 + row];
      const unsigned short* O0 = partO + (size_t)pidx * 8192 + row * 64 + d0;
#pragma unroll
      for (int v = 0; v < 4; v++) {
        u16x4 a = *(const u16x4*)(O0 + v * 4);
#pragma unroll
        for (int e = 0; e < 4; e++) acc[v * 4 + e] += bf2f(a[e]);
      }
    }
    float linv = 1.f / lsum;
    unsigned short* out = Ob + ((size_t)b * SEQ + qt * 128 + row) * EMBED + h * 64 + d0;
    u16x4 res[4];
#pragma unroll
    for (int v = 0; v < 4; v++) {
#pragma unroll
      for (int e = 0; e < 4; e++) res[v][e] = bfbits(acc[v * 4 + e] * linv);
    }
    *(u16x4*)(out)      = res[0];
    *(u16x4*)(out + 4)  = res[1];
    *(u16x4*)(out + 8)  = res[2];
    *(u16x4*)(out + 12) = res[3];
  }
}

extern "C" void kernel_launch(void* const* d_in, const int* in_sizes, int n_in,
                              void* d_out, int out_size, void* d_ws, size_t ws_size,
                              hipStream_t stream) {
  const float* x    = (const float*)d_in[0];
  const float* Wqkv = (const float*)d_in[1];
  const float* bqkv = (const float*)d_in[2];
  const float* Wout = (const float*)d_in[3];
  const float* bout = (const float*)d_in[4];
  float* out = (float*)d_out;

  char* ws = (char*)d_ws;
  // Region [0, 14MB): xb (8MB) + wqkvT (6MB), both dead after gemm1.
  //   After gemm1: partO = 864 slots * 16KB = 14,155,776 B at ws+0,
  //                lbuf  = 864 * 128 * 4  =    442,368 B at ws+14,155,776
  //                (total 14,598,144 < 14,680,064 = woutT offset). Verified.
  unsigned short* xb    = (unsigned short*)ws;
  unsigned short* wqkvT = (unsigned short*)(ws + (size_t)8 * 1048576);
  unsigned short* partO = (unsigned short*)ws;
  float*          lbuf  = (float*)(ws + 14155776);
  unsigned short* woutT = (unsigned short*)(ws + (size_t)14 * 1048576); // 2 MB (live for gemm2)
  unsigned short* qk    = (unsigned short*)(ws + (size_t)16 * 1048576); // 16 MB [2][B][H][T][D]
  unsigned short* vT    = (unsigned short*)(ws + (size_t)32 * 1048576); // 8 MB  [B*H][D][T]
  unsigned short* obuf  = (unsigned short*)(ws + (size_t)40 * 1048576); // 8 MB  [B][T][C]

  prep<<<dim3(4096 + 768 + 256), 256, 0, stream>>>(x, xb, Wqkv, wqkvT, Wout, woutT);

  gemm_bt<128, 0><<<dim3(24, 32), 256, 0, stream>>>(xb, wqkvT, bqkv, qk, vT, nullptr,
                                                    MTOK, 3 * EMBED, EMBED);

  const unsigned short* Qb = qk;
  const unsigned short* Kb = qk + (size_t)BATCH * NH * SEQ * HD;
  attn12<<<dim3(32 * 32), 256, 0, stream>>>(Qb, Kb, vT, obuf, partO, lbuf);
  attn_combine<<<dim3(11 * 32), 256, 0, stream>>>(partO, lbuf, obuf);

  gemm_bt<128, 1><<<dim3(8, 32), 256, 0, stream>>>(obuf, woutT, bout, nullptr, nullptr, out,
                                                   MTOK, EMBED, EMBED);
}

// Round 20
// 101.471 us; speedup vs baseline: 1.0812x; 1.0288x over previous
//
#include <hip/hip_runtime.h>
#include <hip/hip_bf16.h>
#include <stdint.h>

#define EMBED 1024
#define NH 16
#define HD 64
#define BATCH 2
#define SEQ 2048
#define MTOK (BATCH*SEQ)   // 4096

using bf8 = __attribute__((ext_vector_type(8))) short;     // 8 bf16 = one MFMA A/B frag
using f4  = __attribute__((ext_vector_type(4))) float;     // 16x16 C/D frag
using f16v = __attribute__((ext_vector_type(16))) float;   // 32x32 C/D frag
using u16x4 = __attribute__((ext_vector_type(4))) unsigned short;

union U4 { uint32_t u[4]; bf8 v; };

__device__ __forceinline__ uint32_t pk_bf16(float a, float b) {
  __hip_bfloat162 h = __float22bfloat162_rn(float2{a, b});
  union { __hip_bfloat162 h; uint32_t u; } c; c.h = h; return c.u;
}
__device__ __forceinline__ unsigned short bfbits(float f) {
  __hip_bfloat16 h = __float2bfloat16(f);
  union { __hip_bfloat16 h; unsigned short u; } c; c.h = h; return c.u;
}
__device__ __forceinline__ float bf2f(unsigned short u) {
  union { uint32_t u; float f; } c; c.u = (uint32_t)u << 16; return c.f;
}
__device__ __forceinline__ float fexp2(float x) {
#if __has_builtin(__builtin_amdgcn_exp2f)
  return __builtin_amdgcn_exp2f(x);
#else
  return exp2f(x);
#endif
}
__device__ __forceinline__ float frcp(float x) {
#if __has_builtin(__builtin_amdgcn_rcpf)
  return __builtin_amdgcn_rcpf(x);
#else
  return 1.f / x;
#endif
}

__device__ __forceinline__ void gl2lds16(const void* g, void* l) {
  __builtin_amdgcn_global_load_lds(
      (const __attribute__((address_space(1))) void*)g,
      (__attribute__((address_space(3))) void*)l, 16, 0, 0);
}

// ---------------- fused prep: x->bf16 | Wqkv transpose | Wout transpose ----------------
__global__ __launch_bounds__(256) void prep(const float* __restrict__ x,
                                            unsigned short* __restrict__ xb,
                                            const float* __restrict__ Wqkv,
                                            unsigned short* __restrict__ wqkvT,
                                            const float* __restrict__ Wout,
                                            unsigned short* __restrict__ woutT) {
  __shared__ float tl[64][65];
  int blk = blockIdx.x;
  if (blk < 4096) {                              // fp32 -> bf16, 1024 elems/block
    int i = (blk * 256 + threadIdx.x) * 4;
    float4 v = *(const float4*)(x + i);
    uint2 o;
    o.x = pk_bf16(v.x, v.y);
    o.y = pk_bf16(v.z, v.w);
    *(uint2*)(xb + i) = o;
    return;
  }
  const float* W; unsigned short* Wt; int K, N, bx, by;
  if (blk < 4096 + 768) {
    int j = blk - 4096; W = Wqkv; Wt = wqkvT; K = 1024; N = 3072;
    bx = j % 48; by = j / 48;
  } else {
    int j = blk - 4096 - 768; W = Wout; Wt = woutT; K = 1024; N = 1024;
    bx = j % 16; by = j / 16;
  }
  int k0 = by * 64, n0 = bx * 64;
  int tr = threadIdx.x >> 6, tc = threadIdx.x & 63;
#pragma unroll
  for (int i = 0; i < 16; i++) {
    int r = tr + i * 4;
    tl[r][tc] = W[(size_t)(k0 + r) * N + n0 + tc];
  }
  __syncthreads();
#pragma unroll
  for (int i = 0; i < 16; i++) {
    int r = tr + i * 4;
    Wt[(size_t)(n0 + r) * K + k0 + tc] = bfbits(tl[tc][r]);
  }
}

// ---------------- pipelined bf16 GEMM: C[M][N] = A[M][K]*Bt[N][K]^T + bias ----------------
// BM=128, BN in {64,128}, BK=64, double-buffered LDS, counted-vmcnt schedule.
template<int BN, int MODE>
__global__ __launch_bounds__(256) void gemm_bt(const unsigned short* __restrict__ A,
                                               const unsigned short* __restrict__ Bt,
                                               const float* __restrict__ bias,
                                               unsigned short* __restrict__ Oq,
                                               unsigned short* __restrict__ Ov,
                                               float* __restrict__ Of,
                                               int M, int N, int K) {
  constexpr int MT = (BN == 128) ? 4 : 2;
  constexpr int BB = BN * 128;                   // bytes per B buffer
  const int tid = threadIdx.x;
  const int w = tid >> 6, lane = tid & 63;
  const int wm = (BN == 128) ? (w >> 1) : w;
  const int wn = (BN == 128) ? (w & 1) : 0;
  const int m0 = blockIdx.y * 128, n0 = blockIdx.x * BN;

  __shared__ char smem[32768 + 2 * BB];          // A dbuf 2x16K | B dbuf 2xBB

  f4 acc[MT][4] = {};

  auto STAGE = [&](int buf, int kk) {
    int k0 = kk * 64;
#pragma unroll
    for (int i = 0; i < 4; i++) {                // A: 16 chunks of 8 rows
      int c = i * 4 + w;
      int row = c * 8 + (lane >> 3);
      int col = ((lane & 7) * 8) ^ ((row & 7) << 3);
      gl2lds16(A + (size_t)(m0 + row) * K + k0 + col, smem + buf * 16384 + c * 1024);
    }
#pragma unroll
    for (int i = 0; i < BN / 32; i++) {          // B: BN/8 chunks of 8 rows
      int c = i * 4 + w;
      int row = c * 8 + (lane >> 3);
      int col = ((lane & 7) * 8) ^ ((row & 7) << 3);
      gl2lds16(Bt + (size_t)(n0 + row) * K + k0 + col, smem + 32768 + buf * BB + c * 1024);
    }
  };

  const int nk = K / 64;
  STAGE(0, 0);
  STAGE(1, 1);

  for (int kk = 0; kk < nk; kk++) {
    if (kk + 1 < nk) {
      if constexpr (BN == 128) { asm volatile("s_waitcnt vmcnt(8)" ::: "memory"); }
      else                     { asm volatile("s_waitcnt vmcnt(6)" ::: "memory"); }
    } else {
      asm volatile("s_waitcnt vmcnt(0)" ::: "memory");
    }
    __builtin_amdgcn_s_barrier();                // buf[kk&1] ready for all waves

    const char* Al = smem + (kk & 1) * 16384;
    const char* Bl = smem + 32768 + (kk & 1) * BB;
    __builtin_amdgcn_s_setprio(1);
#pragma unroll
    for (int ks = 0; ks < 2; ks++) {
      bf8 af[MT], bfr[4];
#pragma unroll
      for (int mt = 0; mt < MT; mt++) {
        int rr = wm * (MT * 16) + mt * 16 + (lane & 15);
        af[mt] = *(const bf8*)(Al + rr * 128 + ((ks * 64 + (lane >> 4) * 16) ^ ((rr & 7) << 4)));
      }
#pragma unroll
      for (int nt = 0; nt < 4; nt++) {
        int rr = wn * 64 + nt * 16 + (lane & 15);
        bfr[nt] = *(const bf8*)(Bl + rr * 128 + ((ks * 64 + (lane >> 4) * 16) ^ ((rr & 7) << 4)));
      }
#pragma unroll
      for (int mt = 0; mt < MT; mt++)
#pragma unroll
        for (int nt = 0; nt < 4; nt++)
          acc[mt][nt] = __builtin_amdgcn_mfma_f32_16x16x32_bf16(af[mt], bfr[nt], acc[mt][nt], 0, 0, 0);
    }
    __builtin_amdgcn_s_setprio(0);

    __builtin_amdgcn_s_barrier();                // all waves done reading buf[kk&1]
    if (kk + 2 < nk) STAGE(kk & 1, kk + 2);      // overwrite with tile kk+2
  }

  if (MODE == 0) {
    const int region = n0 >> 10;                 // uniform across block
    if (region < 2) {                            // Q or K scatter
      float sc = (region == 0) ? 0.180336880f : 1.0f;  // 1/8 * log2(e) folded into Q
#pragma unroll
      for (int nt = 0; nt < 4; nt++) {
        int n = n0 + wn * 64 + nt * 16 + (lane & 15);
        float bv = bias[n];
        int c = n & 1023, h = c >> 6, d = c & 63;
#pragma unroll
        for (int mt = 0; mt < MT; mt++) {
#pragma unroll
          for (int r = 0; r < 4; r++) {
            int m = m0 + wm * (MT * 16) + mt * 16 + (lane >> 4) * 4 + r;
            int b = m >> 11, t = m & 2047;
            size_t off = ((((size_t)region * 2 + b) * 16 + h) * 2048 + t) * 64 + d;
            Oq[off] = bfbits((acc[mt][nt][r] + bv) * sc);
          }
        }
      }
    } else {                                     // V transposed, t-contiguous b64
#pragma unroll
      for (int nt = 0; nt < 4; nt++) {
        int n = n0 + wn * 64 + nt * 16 + (lane & 15);
        float bv = bias[n];
        int c = n & 1023, h = c >> 6, d = c & 63;
#pragma unroll
        for (int mt = 0; mt < MT; mt++) {
          int m = m0 + wm * (MT * 16) + mt * 16 + (lane >> 4) * 4;
          int b = m >> 11, t = m & 2047;
          size_t off = (((size_t)b * 16 + h) * 64 + d) * 2048 + t;
          u16x4 pk4;
#pragma unroll
          for (int r = 0; r < 4; r++) pk4[r] = bfbits(acc[mt][nt][r] + bv);
          *(u16x4*)(Ov + off) = pk4;
        }
      }
    }
  } else {
#pragma unroll
    for (int mt = 0; mt < MT; mt++) {
#pragma unroll
      for (int r = 0; r < 4; r++) {
        int m = m0 + wm * (MT * 16) + mt * 16 + (lane >> 4) * 4 + r;
#pragma unroll
        for (int nt = 0; nt < 4; nt++) {
          int n = n0 + wn * 64 + nt * 16 + (lane & 15);
          Of[(size_t)m * N + n] = acc[mt][nt][r] + bias[n];
        }
      }
    }
  }
}

// ---------------- causal flash attention v14: 24 segments/bh, single-round residency ----
// Same proven v12 kernel body (tri-buffer, 1 barrier/tile, counted-vmcnt); new work
// partition: 768 blocks = EXACTLY 3/CU (48KB LDS -> 3-block capacity, 144KB) so the
// whole grid is resident in one dispatch round. qt>=8 split into two halves; qt<8
// single-segment direct store. LPT-descending order balances co-resident triples.
__global__ __launch_bounds__(256) void attn14(const unsigned short* __restrict__ Qb,
                                              const unsigned short* __restrict__ Kb,
                                              const unsigned short* __restrict__ Vtb,
                                              unsigned short* __restrict__ Ob,
                                              unsigned short* __restrict__ partO,
                                              float* __restrict__ Lbuf) {
  static const signed char QTs[24] = {15,15, 7,14,14,13,13, 6,12,12,11,11, 5,10,10, 9, 9, 4, 8, 8, 3, 2, 1, 0};
  static const signed char TSs[24] = { 0,16, 0, 0,15, 0,14, 0, 0,13, 0,12, 0, 0,11, 0,10, 0, 0, 9, 0, 0, 0, 0};
  static const signed char TEs[24] = {16,32,16,15,30,14,28,14,13,26,12,24,12,11,22,10,20,10, 9,18, 8, 6, 4, 2};
  static const signed char PS[24]  = { 0, 1,-1, 2, 3, 4, 5,-1, 6, 7, 8, 9,-1,10,11,12,13,-1,14,15,-1,-1,-1,-1};
  const int idx = blockIdx.x;
  const int s = idx >> 5, bh = idx & 31;
  const int qt = QTs[s], ts = TSs[s], te = TEs[s];
  const int slot = PS[s];                        // -1 => direct store

  const int tid = threadIdx.x;
  const int w = tid >> 6, lane = tid & 63;
  const int hi = lane >> 5, q32 = lane & 31;

  __shared__ char smem[49152];                   // K tri-buf 3x8K | Vt tri-buf 3x8K at +24576

  const unsigned short* Qg  = Qb  + (size_t)bh * SEQ * HD;
  const unsigned short* Kg  = Kb  + (size_t)bh * SEQ * HD;
  const unsigned short* Vtg = Vtb + (size_t)bh * SEQ * HD;  // [64 d][2048 t]

  const int qbw  = qt * 128 + w * 32;            // wave's first q-row
  const int qrow = qbw + q32;                    // this lane's q-row (S/P col)

  bf8 qf[4];                                     // Q[qrow][kc*16 + hi*8 + e]
#pragma unroll
  for (int kc = 0; kc < 4; kc++)
    qf[kc] = *(const bf8*)(Qg + (size_t)qrow * HD + kc * 16 + hi * 8);

  f16v acc0 = {}, acc1 = {};                     // O[q][d], d-blocks 0..31 / 32..63
  float lr = 0.f;                                // per-lane partial row-sum

  auto STAGE = [&](int buf, int t) {
    int kv0 = t * 64;
#pragma unroll
    for (int i = 0; i < 2; i++) {
      int c = i * 4 + w;                         // 8 chunks of 8 rows, split across 4 waves
      int row = c * 8 + (lane >> 3);
      int col = ((lane & 7) * 8) ^ ((row & 7) << 3);   // pre-swizzled source
      gl2lds16(Kg + (size_t)(kv0 + row) * HD + col,    smem + buf * 8192 + c * 1024);
      gl2lds16(Vtg + (size_t)row * SEQ + kv0 + col,    smem + 24576 + buf * 8192 + c * 1024);
    }
  };

  const int nt_loc = te - ts;
  STAGE(0, ts);                                  // 2-deep prefetch prologue
  if (nt_loc > 1) STAGE(1, ts + 1);

  for (int tl = 0; tl < nt_loc; tl++) {
    const int t = ts + tl;
    const int kv0 = t * 64;

    if (tl + 1 < nt_loc) {
      asm volatile("s_waitcnt vmcnt(4)" ::: "memory");
    } else {
      asm volatile("s_waitcnt vmcnt(0)" ::: "memory");
    }
    __builtin_amdgcn_s_barrier();                // single barrier: tile tl ready everywhere
    if (tl + 2 < nt_loc) STAGE((tl + 2) % 3, t + 2);   // issue early; hides under compute

    if (kv0 <= qbw + 31) {                       // wave-uniform: skip fully-masked tiles
      const char* kl = smem + (tl % 3) * 8192;
      const char* vl = smem + 24576 + (tl % 3) * 8192;
      const bool hi_vis = (kv0 + 32 <= qbw + 31);  // upper key-half visible?

      // S^T = K Q^T (zero C-init; softmax is shift-invariant)
      f16v s0 = {}, s1 = {};
      __builtin_amdgcn_s_setprio(1);
#pragma unroll
      for (int kc = 0; kc < 4; kc++) {
        int r0 = q32;
        bf8 k0 = *(const bf8*)(kl + r0 * 128 + ((kc * 32 + hi * 16) ^ ((r0 & 7) << 4)));
        s0 = __builtin_amdgcn_mfma_f32_32x32x16_bf16(k0, qf[kc], s0, 0, 0, 0);
      }
      if (hi_vis) {
#pragma unroll
        for (int kc = 0; kc < 4; kc++) {
          int r1 = 32 + q32;
          bf8 k1 = *(const bf8*)(kl + r1 * 128 + ((kc * 32 + hi * 16) ^ ((r1 & 7) << 4)));
          s1 = __builtin_amdgcn_mfma_f32_32x32x16_bf16(k1, qf[kc], s1, 0, 0, 0);
        }
      }
      __builtin_amdgcn_s_setprio(0);

      if (kv0 + 63 > qbw) {                      // diagonal overlap: mask
#pragma unroll
        for (int r = 0; r < 16; r++) {
          int key = kv0 + (r & 3) + 8 * (r >> 2) + 4 * hi;
          if (key > qrow)      s0[r] = -1e30f;
          if (key + 32 > qrow) s1[r] = -1e30f;
        }
      }

      // P = exp2(S) -> packed bf16 words; l accumulates per-lane (lane-local q-row)
      uint32_t u[16];
#pragma unroll
      for (int m8 = 0; m8 < 8; m8++) {
        float pa = fexp2(s0[2 * m8]), pb = fexp2(s0[2 * m8 + 1]);
        lr += pa + pb;
        u[m8] = pk_bf16(pa, pb);
      }
      if (hi_vis) {
#pragma unroll
        for (int m8 = 0; m8 < 8; m8++) {
          float pc = fexp2(s1[2 * m8]), pd = fexp2(s1[2 * m8 + 1]);
          lr += pc + pd;
          u[8 + m8] = pk_bf16(pc, pd);
        }
      }

      // O += P V  (A-frag via permlane32_swap, no selects)
      __builtin_amdgcn_s_setprio(1);
      const int ncc = hi_vis ? 4 : 2;
      for (int kcc = 0; kcc < ncc; kcc++) {
        const int base = (kcc >> 1) * 8 + (kcc & 1) * 4;
        uint32_t a0 = u[base + 0], a2 = u[base + 2];
        uint32_t a1 = u[base + 1], a3 = u[base + 3];
        asm("v_permlane32_swap_b32 %0, %1" : "+v"(a0), "+v"(a2));
        asm("v_permlane32_swap_b32 %0, %1" : "+v"(a1), "+v"(a3));
        U4 f; f.u[0] = a0; f.u[1] = a1; f.u[2] = a2; f.u[3] = a3;
        int r0 = q32, r1 = 32 + q32;
        bf8 v0 = *(const bf8*)(vl + r0 * 128 + ((kcc * 32 + hi * 16) ^ ((r0 & 7) << 4)));
        bf8 v1 = *(const bf8*)(vl + r1 * 128 + ((kcc * 32 + hi * 16) ^ ((r1 & 7) << 4)));
        acc0 = __builtin_amdgcn_mfma_f32_32x32x16_bf16(f.v, v0, acc0, 0, 0, 0);
        acc1 = __builtin_amdgcn_mfma_f32_32x32x16_bf16(f.v, v1, acc1, 0, 0, 0);
      }
      __builtin_amdgcn_s_setprio(0);
    }
  }

  // finalize: total l per q-row = lr(hi=0) + lr(hi=1); lane q32 owns q-row q32.
  lr += __shfl_xor(lr, 32);
  if (slot < 0) {                                // single segment: normalize + store
    int b = bh >> 4, h = bh & 15;
    unsigned short* Og = Ob + (size_t)b * SEQ * EMBED;
#pragma unroll
    for (int r = 0; r < 16; r++) {
      int ql_ = (r & 3) + 8 * (r >> 2) + 4 * hi;
      float linv = frcp(__shfl(lr, ql_));
      size_t rowoff = (size_t)(qbw + ql_) * EMBED + h * 64;
      Og[rowoff + q32]      = bfbits(acc0[r] * linv);
      Og[rowoff + 32 + q32] = bfbits(acc1[r] * linv);
    }
  } else {                                       // partial: unnormalized bf16 O + l
    int pidx = slot * 32 + bh;
    unsigned short* P0 = partO + (size_t)pidx * 8192;   // [128 q][64 d]
#pragma unroll
    for (int r = 0; r < 16; r++) {
      int ql_ = (r & 3) + 8 * (r >> 2) + 4 * hi;
      int rowl = w * 32 + ql_;
      P0[rowl * 64 + q32]      = bfbits(acc0[r]);
      P0[rowl * 64 + 32 + q32] = bfbits(acc1[r]);
    }
    if (hi == 0) Lbuf[pidx * 128 + w * 32 + q32] = lr;   // lanes 0..31: one row each
  }
}

// ---------------- combine 2 KV-segments (linear merge), qt = 8..15 ----------------
__global__ __launch_bounds__(256) void attn_combine(const unsigned short* __restrict__ partO,
                                                    const float* __restrict__ Lbuf,
                                                    unsigned short* __restrict__ Ob) {
  int pair = blockIdx.x;                 // qi*32 + bh, qi = qt-8
  int qi = pair >> 5, bh = pair & 31;
  int qt = 8 + qi;
  int base = (15 - qt) * 2;              // slots base, base+1
  int b = bh >> 4, h = bh & 15;
#pragma unroll
  for (int rr = 0; rr < 2; rr++) {
    int row = rr * 64 + (threadIdx.x >> 2);   // 0..127
    int d0 = (threadIdx.x & 3) * 16;          // 16 d-elems per thread
    int p0 = (base + 0) * 32 + bh, p1 = (base + 1) * 32 + bh;
    float lsum = Lbuf[p0 * 128 + row] + Lbuf[p1 * 128 + row];
    float linv = 1.f / lsum;
    const unsigned short* O0 = partO + (size_t)p0 * 8192 + row * 64 + d0;
    const unsigned short* O1 = partO + (size_t)p1 * 8192 + row * 64 + d0;
    unsigned short* out = Ob + ((size_t)b * SEQ + qt * 128 + row) * EMBED + h * 64 + d0;
    u16x4 res[4];
#pragma unroll
    for (int v = 0; v < 4; v++) {
      u16x4 a = *(const u16x4*)(O0 + v * 4);
      u16x4 c = *(const u16x4*)(O1 + v * 4);
#pragma unroll
      for (int e = 0; e < 4; e++)
        res[v][e] = bfbits(linv * (bf2f(a[e]) + bf2f(c[e])));
    }
    *(u16x4*)(out)      = res[0];
    *(u16x4*)(out + 4)  = res[1];
    *(u16x4*)(out + 8)  = res[2];
    *(u16x4*)(out + 12) = res[3];
  }
}

extern "C" void kernel_launch(void* const* d_in, const int* in_sizes, int n_in,
                              void* d_out, int out_size, void* d_ws, size_t ws_size,
                              hipStream_t stream) {
  const float* x    = (const float*)d_in[0];
  const float* Wqkv = (const float*)d_in[1];
  const float* bqkv = (const float*)d_in[2];
  const float* Wout = (const float*)d_in[3];
  const float* bout = (const float*)d_in[4];
  float* out = (float*)d_out;

  char* ws = (char*)d_ws;
  // Region [0, 14MB): xb (8MB) + wqkvT (6MB), both dead after gemm1.
  //   After gemm1: partO = 512 slots * 16KB = 8,388,608 B at ws+0,
  //                lbuf  = 512 * 128 * 4  =   262,144 B at ws+8,388,608
  //                (total 8,650,752 < 14,680,064 = woutT offset). Verified.
  unsigned short* xb    = (unsigned short*)ws;
  unsigned short* wqkvT = (unsigned short*)(ws + (size_t)8 * 1048576);
  unsigned short* partO = (unsigned short*)ws;
  float*          lbuf  = (float*)(ws + 8388608);
  unsigned short* woutT = (unsigned short*)(ws + (size_t)14 * 1048576); // 2 MB (live for gemm2)
  unsigned short* qk    = (unsigned short*)(ws + (size_t)16 * 1048576); // 16 MB [2][B][H][T][D]
  unsigned short* vT    = (unsigned short*)(ws + (size_t)32 * 1048576); // 8 MB  [B*H][D][T]
  unsigned short* obuf  = (unsigned short*)(ws + (size_t)40 * 1048576); // 8 MB  [B][T][C]

  prep<<<dim3(4096 + 768 + 256), 256, 0, stream>>>(x, xb, Wqkv, wqkvT, Wout, woutT);

  gemm_bt<128, 0><<<dim3(24, 32), 256, 0, stream>>>(xb, wqkvT, bqkv, qk, vT, nullptr,
                                                    MTOK, 3 * EMBED, EMBED);

  const unsigned short* Qb = qk;
  const unsigned short* Kb = qk + (size_t)BATCH * NH * SEQ * HD;
  attn14<<<dim3(24 * 32), 256, 0, stream>>>(Qb, Kb, vT, obuf, partO, lbuf);
  attn_combine<<<dim3(8 * 32), 256, 0, stream>>>(partO, lbuf, obuf);

  gemm_bt<128, 1><<<dim3(8, 32), 256, 0, stream>>>(obuf, woutT, bout, nullptr, nullptr, out,
                                                   MTOK, EMBED, EMBED);
}

// Round 21
// 100.997 us; speedup vs baseline: 1.0863x; 1.0047x over previous
//
#include <hip/hip_runtime.h>
#include <hip/hip_bf16.h>
#include <stdint.h>

#define EMBED 1024
#define NH 16
#define HD 64
#define BATCH 2
#define SEQ 2048
#define MTOK (BATCH*SEQ)   // 4096

using bf8 = __attribute__((ext_vector_type(8))) short;     // 8 bf16 = one MFMA A/B frag
using f4  = __attribute__((ext_vector_type(4))) float;     // 16x16 C/D frag
using f16v = __attribute__((ext_vector_type(16))) float;   // 32x32 C/D frag
using u16x4 = __attribute__((ext_vector_type(4))) unsigned short;

union U4 { uint32_t u[4]; bf8 v; };

__device__ __forceinline__ uint32_t pk_bf16(float a, float b) {
  __hip_bfloat162 h = __float22bfloat162_rn(float2{a, b});
  union { __hip_bfloat162 h; uint32_t u; } c; c.h = h; return c.u;
}
__device__ __forceinline__ unsigned short bfbits(float f) {
  __hip_bfloat16 h = __float2bfloat16(f);
  union { __hip_bfloat16 h; unsigned short u; } c; c.h = h; return c.u;
}
__device__ __forceinline__ float bf2f(unsigned short u) {
  union { uint32_t u; float f; } c; c.u = (uint32_t)u << 16; return c.f;
}
__device__ __forceinline__ float fexp2(float x) {
#if __has_builtin(__builtin_amdgcn_exp2f)
  return __builtin_amdgcn_exp2f(x);
#else
  return exp2f(x);
#endif
}
__device__ __forceinline__ float frcp(float x) {
#if __has_builtin(__builtin_amdgcn_rcpf)
  return __builtin_amdgcn_rcpf(x);
#else
  return 1.f / x;
#endif
}

__device__ __forceinline__ void gl2lds16(const void* g, void* l) {
  __builtin_amdgcn_global_load_lds(
      (const __attribute__((address_space(1))) void*)g,
      (__attribute__((address_space(3))) void*)l, 16, 0, 0);
}

// ---------------- fused prep: x->bf16 | Wqkv transpose | Wout transpose ----------------
__global__ __launch_bounds__(256) void prep(const float* __restrict__ x,
                                            unsigned short* __restrict__ xb,
                                            const float* __restrict__ Wqkv,
                                            unsigned short* __restrict__ wqkvT,
                                            const float* __restrict__ Wout,
                                            unsigned short* __restrict__ woutT) {
  __shared__ float tl[64][65];
  int blk = blockIdx.x;
  if (blk < 4096) {                              // fp32 -> bf16, 1024 elems/block
    int i = (blk * 256 + threadIdx.x) * 4;
    float4 v = *(const float4*)(x + i);
    uint2 o;
    o.x = pk_bf16(v.x, v.y);
    o.y = pk_bf16(v.z, v.w);
    *(uint2*)(xb + i) = o;
    return;
  }
  const float* W; unsigned short* Wt; int K, N, bx, by;
  if (blk < 4096 + 768) {
    int j = blk - 4096; W = Wqkv; Wt = wqkvT; K = 1024; N = 3072;
    bx = j % 48; by = j / 48;
  } else {
    int j = blk - 4096 - 768; W = Wout; Wt = woutT; K = 1024; N = 1024;
    bx = j % 16; by = j / 16;
  }
  int k0 = by * 64, n0 = bx * 64;
  int tr = threadIdx.x >> 6, tc = threadIdx.x & 63;
#pragma unroll
  for (int i = 0; i < 16; i++) {
    int r = tr + i * 4;
    tl[r][tc] = W[(size_t)(k0 + r) * N + n0 + tc];
  }
  __syncthreads();
#pragma unroll
  for (int i = 0; i < 16; i++) {
    int r = tr + i * 4;
    Wt[(size_t)(n0 + r) * K + k0 + tc] = bfbits(tl[tc][r]);
  }
}

// ---------------- pipelined bf16 GEMM: C[M][N] = A[M][K]*Bt[N][K]^T + bias ----------------
// BM=128, BN in {64,128}, BK=64, double-buffered LDS, counted-vmcnt schedule.
template<int BN, int MODE>
__global__ __launch_bounds__(256) void gemm_bt(const unsigned short* __restrict__ A,
                                               const unsigned short* __restrict__ Bt,
                                               const float* __restrict__ bias,
                                               unsigned short* __restrict__ Oq,
                                               unsigned short* __restrict__ Ov,
                                               float* __restrict__ Of,
                                               int M, int N, int K) {
  constexpr int MT = (BN == 128) ? 4 : 2;
  constexpr int BB = BN * 128;                   // bytes per B buffer
  const int tid = threadIdx.x;
  const int w = tid >> 6, lane = tid & 63;
  const int wm = (BN == 128) ? (w >> 1) : w;
  const int wn = (BN == 128) ? (w & 1) : 0;
  const int m0 = blockIdx.y * 128, n0 = blockIdx.x * BN;

  __shared__ char smem[32768 + 2 * BB];          // A dbuf 2x16K | B dbuf 2xBB

  f4 acc[MT][4] = {};

  auto STAGE = [&](int buf, int kk) {
    int k0 = kk * 64;
#pragma unroll
    for (int i = 0; i < 4; i++) {                // A: 16 chunks of 8 rows
      int c = i * 4 + w;
      int row = c * 8 + (lane >> 3);
      int col = ((lane & 7) * 8) ^ ((row & 7) << 3);
      gl2lds16(A + (size_t)(m0 + row) * K + k0 + col, smem + buf * 16384 + c * 1024);
    }
#pragma unroll
    for (int i = 0; i < BN / 32; i++) {          // B: BN/8 chunks of 8 rows
      int c = i * 4 + w;
      int row = c * 8 + (lane >> 3);
      int col = ((lane & 7) * 8) ^ ((row & 7) << 3);
      gl2lds16(Bt + (size_t)(n0 + row) * K + k0 + col, smem + 32768 + buf * BB + c * 1024);
    }
  };

  const int nk = K / 64;
  STAGE(0, 0);
  STAGE(1, 1);

  for (int kk = 0; kk < nk; kk++) {
    if (kk + 1 < nk) {
      if constexpr (BN == 128) { asm volatile("s_waitcnt vmcnt(8)" ::: "memory"); }
      else                     { asm volatile("s_waitcnt vmcnt(6)" ::: "memory"); }
    } else {
      asm volatile("s_waitcnt vmcnt(0)" ::: "memory");
    }
    __builtin_amdgcn_s_barrier();                // buf[kk&1] ready for all waves

    const char* Al = smem + (kk & 1) * 16384;
    const char* Bl = smem + 32768 + (kk & 1) * BB;
    __builtin_amdgcn_s_setprio(1);
#pragma unroll
    for (int ks = 0; ks < 2; ks++) {
      bf8 af[MT], bfr[4];
#pragma unroll
      for (int mt = 0; mt < MT; mt++) {
        int rr = wm * (MT * 16) + mt * 16 + (lane & 15);
        af[mt] = *(const bf8*)(Al + rr * 128 + ((ks * 64 + (lane >> 4) * 16) ^ ((rr & 7) << 4)));
      }
#pragma unroll
      for (int nt = 0; nt < 4; nt++) {
        int rr = wn * 64 + nt * 16 + (lane & 15);
        bfr[nt] = *(const bf8*)(Bl + rr * 128 + ((ks * 64 + (lane >> 4) * 16) ^ ((rr & 7) << 4)));
      }
#pragma unroll
      for (int mt = 0; mt < MT; mt++)
#pragma unroll
        for (int nt = 0; nt < 4; nt++)
          acc[mt][nt] = __builtin_amdgcn_mfma_f32_16x16x32_bf16(af[mt], bfr[nt], acc[mt][nt], 0, 0, 0);
    }
    __builtin_amdgcn_s_setprio(0);

    __builtin_amdgcn_s_barrier();                // all waves done reading buf[kk&1]
    if (kk + 2 < nk) STAGE(kk & 1, kk + 2);      // overwrite with tile kk+2
  }

  if (MODE == 0) {
    const int region = n0 >> 10;                 // uniform across block
    if (region < 2) {                            // Q or K scatter
      float sc = (region == 0) ? 0.180336880f : 1.0f;  // 1/8 * log2(e) folded into Q
#pragma unroll
      for (int nt = 0; nt < 4; nt++) {
        int n = n0 + wn * 64 + nt * 16 + (lane & 15);
        float bv = bias[n];
        int c = n & 1023, h = c >> 6, d = c & 63;
#pragma unroll
        for (int mt = 0; mt < MT; mt++) {
#pragma unroll
          for (int r = 0; r < 4; r++) {
            int m = m0 + wm * (MT * 16) + mt * 16 + (lane >> 4) * 4 + r;
            int b = m >> 11, t = m & 2047;
            size_t off = ((((size_t)region * 2 + b) * 16 + h) * 2048 + t) * 64 + d;
            Oq[off] = bfbits((acc[mt][nt][r] + bv) * sc);
          }
        }
      }
    } else {                                     // V transposed, t-contiguous b64
#pragma unroll
      for (int nt = 0; nt < 4; nt++) {
        int n = n0 + wn * 64 + nt * 16 + (lane & 15);
        float bv = bias[n];
        int c = n & 1023, h = c >> 6, d = c & 63;
#pragma unroll
        for (int mt = 0; mt < MT; mt++) {
          int m = m0 + wm * (MT * 16) + mt * 16 + (lane >> 4) * 4;
          int b = m >> 11, t = m & 2047;
          size_t off = (((size_t)b * 16 + h) * 64 + d) * 2048 + t;
          u16x4 pk4;
#pragma unroll
          for (int r = 0; r < 4; r++) pk4[r] = bfbits(acc[mt][nt][r] + bv);
          *(u16x4*)(Ov + off) = pk4;
        }
      }
    }
  } else {
#pragma unroll
    for (int mt = 0; mt < MT; mt++) {
#pragma unroll
      for (int r = 0; r < 4; r++) {
        int m = m0 + wm * (MT * 16) + mt * 16 + (lane >> 4) * 4 + r;
#pragma unroll
        for (int nt = 0; nt < 4; nt++) {
          int n = n0 + wn * 64 + nt * 16 + (lane & 15);
          Of[(size_t)m * N + n] = acc[mt][nt][r] + bias[n];
        }
      }
    }
  }
}

// ---------------- causal flash attention v15: perfectly balanced triples ----------------
// Same proven v12/v14 kernel body; 24 segments/bh = 768 blocks = exactly 3/CU.
// Dispatch gives CU c the triple (s, s+8, s+16); table arranged so EVERY triple
// sums to 34 tiles: (16,16,2)(16,14,4)(15,13,6)(15,11,8)(14,11,9)(14,10,10)
// (13,12,9)(12,12,10). Slots keep the (15-qt)*2+{0,1} convention for combine.
__global__ __launch_bounds__(256) void attn15(const unsigned short* __restrict__ Qb,
                                              const unsigned short* __restrict__ Kb,
                                              const unsigned short* __restrict__ Vtb,
                                              unsigned short* __restrict__ Ob,
                                              unsigned short* __restrict__ partO,
                                              float* __restrict__ Lbuf) {
  static const signed char QTs[24] = {15, 7,14,14,13,13,12,11,  15, 6,12,10,10, 9,11, 5,   0, 1, 2, 3, 8, 4, 8, 9};
  static const signed char TSs[24] = { 0, 0, 0,15, 0,14,13,12,  16, 0, 0, 0,11, 0, 0, 0,   0, 0, 0, 0, 0, 0, 9,10};
  static const signed char TEs[24] = {16,16,15,30,14,28,26,24,  32,14,13,11,22,10,12,12,   2, 4, 6, 8, 9,10,18,20};
  static const signed char PS[24]  = { 0,-1, 2, 3, 4, 5, 7, 9,   1,-1, 6,10,11,12, 8,-1,  -1,-1,-1,-1,14,-1,15,13};
  const int idx = blockIdx.x;
  const int s = idx >> 5, bh = idx & 31;
  const int qt = QTs[s], ts = TSs[s], te = TEs[s];
  const int slot = PS[s];                        // -1 => direct store

  const int tid = threadIdx.x;
  const int w = tid >> 6, lane = tid & 63;
  const int hi = lane >> 5, q32 = lane & 31;

  __shared__ char smem[49152];                   // K tri-buf 3x8K | Vt tri-buf 3x8K at +24576

  const unsigned short* Qg  = Qb  + (size_t)bh * SEQ * HD;
  const unsigned short* Kg  = Kb  + (size_t)bh * SEQ * HD;
  const unsigned short* Vtg = Vtb + (size_t)bh * SEQ * HD;  // [64 d][2048 t]

  const int qbw  = qt * 128 + w * 32;            // wave's first q-row
  const int qrow = qbw + q32;                    // this lane's q-row (S/P col)

  bf8 qf[4];                                     // Q[qrow][kc*16 + hi*8 + e]
#pragma unroll
  for (int kc = 0; kc < 4; kc++)
    qf[kc] = *(const bf8*)(Qg + (size_t)qrow * HD + kc * 16 + hi * 8);

  f16v acc0 = {}, acc1 = {};                     // O[q][d], d-blocks 0..31 / 32..63
  float lr = 0.f;                                // per-lane partial row-sum

  auto STAGE = [&](int buf, int t) {
    int kv0 = t * 64;
#pragma unroll
    for (int i = 0; i < 2; i++) {
      int c = i * 4 + w;                         // 8 chunks of 8 rows, split across 4 waves
      int row = c * 8 + (lane >> 3);
      int col = ((lane & 7) * 8) ^ ((row & 7) << 3);   // pre-swizzled source
      gl2lds16(Kg + (size_t)(kv0 + row) * HD + col,    smem + buf * 8192 + c * 1024);
      gl2lds16(Vtg + (size_t)row * SEQ + kv0 + col,    smem + 24576 + buf * 8192 + c * 1024);
    }
  };

  const int nt_loc = te - ts;
  STAGE(0, ts);                                  // 2-deep prefetch prologue
  if (nt_loc > 1) STAGE(1, ts + 1);

  for (int tl = 0; tl < nt_loc; tl++) {
    const int t = ts + tl;
    const int kv0 = t * 64;

    if (tl + 1 < nt_loc) {
      asm volatile("s_waitcnt vmcnt(4)" ::: "memory");
    } else {
      asm volatile("s_waitcnt vmcnt(0)" ::: "memory");
    }
    __builtin_amdgcn_s_barrier();                // single barrier: tile tl ready everywhere
    if (tl + 2 < nt_loc) STAGE((tl + 2) % 3, t + 2);   // issue early; hides under compute

    if (kv0 <= qbw + 31) {                       // wave-uniform: skip fully-masked tiles
      const char* kl = smem + (tl % 3) * 8192;
      const char* vl = smem + 24576 + (tl % 3) * 8192;
      const bool hi_vis = (kv0 + 32 <= qbw + 31);  // upper key-half visible?

      // S^T = K Q^T (zero C-init; softmax is shift-invariant)
      f16v s0 = {}, s1 = {};
      __builtin_amdgcn_s_setprio(1);
#pragma unroll
      for (int kc = 0; kc < 4; kc++) {
        int r0 = q32;
        bf8 k0 = *(const bf8*)(kl + r0 * 128 + ((kc * 32 + hi * 16) ^ ((r0 & 7) << 4)));
        s0 = __builtin_amdgcn_mfma_f32_32x32x16_bf16(k0, qf[kc], s0, 0, 0, 0);
      }
      if (hi_vis) {
#pragma unroll
        for (int kc = 0; kc < 4; kc++) {
          int r1 = 32 + q32;
          bf8 k1 = *(const bf8*)(kl + r1 * 128 + ((kc * 32 + hi * 16) ^ ((r1 & 7) << 4)));
          s1 = __builtin_amdgcn_mfma_f32_32x32x16_bf16(k1, qf[kc], s1, 0, 0, 0);
        }
      }
      __builtin_amdgcn_s_setprio(0);

      if (kv0 + 63 > qbw) {                      // diagonal overlap: mask
#pragma unroll
        for (int r = 0; r < 16; r++) {
          int key = kv0 + (r & 3) + 8 * (r >> 2) + 4 * hi;
          if (key > qrow)      s0[r] = -1e30f;
          if (key + 32 > qrow) s1[r] = -1e30f;
        }
      }

      // P = exp2(S) -> packed bf16 words; l accumulates per-lane (lane-local q-row)
      uint32_t u[16];
#pragma unroll
      for (int m8 = 0; m8 < 8; m8++) {
        float pa = fexp2(s0[2 * m8]), pb = fexp2(s0[2 * m8 + 1]);
        lr += pa + pb;
        u[m8] = pk_bf16(pa, pb);
      }
      if (hi_vis) {
#pragma unroll
        for (int m8 = 0; m8 < 8; m8++) {
          float pc = fexp2(s1[2 * m8]), pd = fexp2(s1[2 * m8 + 1]);
          lr += pc + pd;
          u[8 + m8] = pk_bf16(pc, pd);
        }
      }

      // O += P V  (A-frag via permlane32_swap, no selects)
      __builtin_amdgcn_s_setprio(1);
      const int ncc = hi_vis ? 4 : 2;
      for (int kcc = 0; kcc < ncc; kcc++) {
        const int base = (kcc >> 1) * 8 + (kcc & 1) * 4;
        uint32_t a0 = u[base + 0], a2 = u[base + 2];
        uint32_t a1 = u[base + 1], a3 = u[base + 3];
        asm("v_permlane32_swap_b32 %0, %1" : "+v"(a0), "+v"(a2));
        asm("v_permlane32_swap_b32 %0, %1" : "+v"(a1), "+v"(a3));
        U4 f; f.u[0] = a0; f.u[1] = a1; f.u[2] = a2; f.u[3] = a3;
        int r0 = q32, r1 = 32 + q32;
        bf8 v0 = *(const bf8*)(vl + r0 * 128 + ((kcc * 32 + hi * 16) ^ ((r0 & 7) << 4)));
        bf8 v1 = *(const bf8*)(vl + r1 * 128 + ((kcc * 32 + hi * 16) ^ ((r1 & 7) << 4)));
        acc0 = __builtin_amdgcn_mfma_f32_32x32x16_bf16(f.v, v0, acc0, 0, 0, 0);
        acc1 = __builtin_amdgcn_mfma_f32_32x32x16_bf16(f.v, v1, acc1, 0, 0, 0);
      }
      __builtin_amdgcn_s_setprio(0);
    }
  }

  // finalize: total l per q-row = lr(hi=0) + lr(hi=1); lane q32 owns q-row q32.
  lr += __shfl_xor(lr, 32);
  if (slot < 0) {                                // single segment: normalize + store
    int b = bh >> 4, h = bh & 15;
    unsigned short* Og = Ob + (size_t)b * SEQ * EMBED;
#pragma unroll
    for (int r = 0; r < 16; r++) {
      int ql_ = (r & 3) + 8 * (r >> 2) + 4 * hi;
      float linv = frcp(__shfl(lr, ql_));
      size_t rowoff = (size_t)(qbw + ql_) * EMBED + h * 64;
      Og[rowoff + q32]      = bfbits(acc0[r] * linv);
      Og[rowoff + 32 + q32] = bfbits(acc1[r] * linv);
    }
  } else {                                       // partial: unnormalized bf16 O + l
    int pidx = slot * 32 + bh;
    unsigned short* P0 = partO + (size_t)pidx * 8192;   // [128 q][64 d]
#pragma unroll
    for (int r = 0; r < 16; r++) {
      int ql_ = (r & 3) + 8 * (r >> 2) + 4 * hi;
      int rowl = w * 32 + ql_;
      P0[rowl * 64 + q32]      = bfbits(acc0[r]);
      P0[rowl * 64 + 32 + q32] = bfbits(acc1[r]);
    }
    if (hi == 0) Lbuf[pidx * 128 + w * 32 + q32] = lr;   // lanes 0..31: one row each
  }
}

// ---------------- combine 2 KV-segments (linear merge), qt = 8..15 ----------------
__global__ __launch_bounds__(256) void attn_combine(const unsigned short* __restrict__ partO,
                                                    const float* __restrict__ Lbuf,
                                                    unsigned short* __restrict__ Ob) {
  int pair = blockIdx.x;                 // qi*32 + bh, qi = qt-8
  int qi = pair >> 5, bh = pair & 31;
  int qt = 8 + qi;
  int base = (15 - qt) * 2;              // slots base, base+1
  int b = bh >> 4, h = bh & 15;
#pragma unroll
  for (int rr = 0; rr < 2; rr++) {
    int row = rr * 64 + (threadIdx.x >> 2);   // 0..127
    int d0 = (threadIdx.x & 3) * 16;          // 16 d-elems per thread
    int p0 = (base + 0) * 32 + bh, p1 = (base + 1) * 32 + bh;
    float lsum = Lbuf[p0 * 128 + row] + Lbuf[p1 * 128 + row];
    float linv = 1.f / lsum;
    const unsigned short* O0 = partO + (size_t)p0 * 8192 + row * 64 + d0;
    const unsigned short* O1 = partO + (size_t)p1 * 8192 + row * 64 + d0;
    unsigned short* out = Ob + ((size_t)b * SEQ + qt * 128 + row) * EMBED + h * 64 + d0;
    u16x4 res[4];
#pragma unroll
    for (int v = 0; v < 4; v++) {
      u16x4 a = *(const u16x4*)(O0 + v * 4);
      u16x4 c = *(const u16x4*)(O1 + v * 4);
#pragma unroll
      for (int e = 0; e < 4; e++)
        res[v][e] = bfbits(linv * (bf2f(a[e]) + bf2f(c[e])));
    }
    *(u16x4*)(out)      = res[0];
    *(u16x4*)(out + 4)  = res[1];
    *(u16x4*)(out + 8)  = res[2];
    *(u16x4*)(out + 12) = res[3];
  }
}

extern "C" void kernel_launch(void* const* d_in, const int* in_sizes, int n_in,
                              void* d_out, int out_size, void* d_ws, size_t ws_size,
                              hipStream_t stream) {
  const float* x    = (const float*)d_in[0];
  const float* Wqkv = (const float*)d_in[1];
  const float* bqkv = (const float*)d_in[2];
  const float* Wout = (const float*)d_in[3];
  const float* bout = (const float*)d_in[4];
  float* out = (float*)d_out;

  char* ws = (char*)d_ws;
  // Region [0, 14MB): xb (8MB) + wqkvT (6MB), both dead after gemm1.
  //   After gemm1: partO = 512 slots * 16KB = 8,388,608 B at ws+0,
  //                lbuf  = 512 * 128 * 4  =   262,144 B at ws+8,388,608
  //                (total 8,650,752 < 14,680,064 = woutT offset). Verified.
  unsigned short* xb    = (unsigned short*)ws;
  unsigned short* wqkvT = (unsigned short*)(ws + (size_t)8 * 1048576);
  unsigned short* partO = (unsigned short*)ws;
  float*          lbuf  = (float*)(ws + 8388608);
  unsigned short* woutT = (unsigned short*)(ws + (size_t)14 * 1048576); // 2 MB (live for gemm2)
  unsigned short* qk    = (unsigned short*)(ws + (size_t)16 * 1048576); // 16 MB [2][B][H][T][D]
  unsigned short* vT    = (unsigned short*)(ws + (size_t)32 * 1048576); // 8 MB  [B*H][D][T]
  unsigned short* obuf  = (unsigned short*)(ws + (size_t)40 * 1048576); // 8 MB  [B][T][C]

  prep<<<dim3(4096 + 768 + 256), 256, 0, stream>>>(x, xb, Wqkv, wqkvT, Wout, woutT);

  gemm_bt<128, 0><<<dim3(24, 32), 256, 0, stream>>>(xb, wqkvT, bqkv, qk, vT, nullptr,
                                                    MTOK, 3 * EMBED, EMBED);

  const unsigned short* Qb = qk;
  const unsigned short* Kb = qk + (size_t)BATCH * NH * SEQ * HD;
  attn15<<<dim3(24 * 32), 256, 0, stream>>>(Qb, Kb, vT, obuf, partO, lbuf);
  attn_combine<<<dim3(8 * 32), 256, 0, stream>>>(partO, lbuf, obuf);

  gemm_bt<128, 1><<<dim3(8, 32), 256, 0, stream>>>(obuf, woutT, bout, nullptr, nullptr, out,
                                                   MTOK, EMBED, EMBED);
}